// Round 3
// baseline (1139.081 us; speedup 1.0000x reference)
//
#include <hip/hip_runtime.h>

typedef __bf16 bf16x8 __attribute__((ext_vector_type(8)));
typedef __bf16 bf16x4 __attribute__((ext_vector_type(4)));
typedef __bf16 bf16x2 __attribute__((ext_vector_type(2)));
typedef float f32x4 __attribute__((ext_vector_type(4)));
typedef unsigned int u32;

// Problem constants: B (runtime), S=2048, D=1024, H=16, hd=64
#define QSCALE 0.18033688011112042f  // hd^-0.5 * log2(e), folded into Q

__device__ __forceinline__ void gld_lds16(const void* gsrc, void* ldst) {
  __builtin_amdgcn_global_load_lds(
      (const __attribute__((address_space(1))) u32*)gsrc,
      (__attribute__((address_space(3))) u32*)ldst, 16, 0, 0);
}

__device__ __forceinline__ float fexp2(float x) {
#if __has_builtin(__builtin_amdgcn_exp2f)
  return __builtin_amdgcn_exp2f(x);
#else
  return exp2f(x);
#endif
}

__device__ __forceinline__ u32 pkbf(float a, float b) {
  bf16x2 t; t[0] = (__bf16)a; t[1] = (__bf16)b;
  return __builtin_bit_cast(u32, t);
}

// ---------------- fp32 -> bf16 elementwise convert ----------------
__global__ __launch_bounds__(256) void cvt_f32_bf16(const float* __restrict__ src,
                                                    __bf16* __restrict__ dst, int n) {
  int i = (blockIdx.x * 256 + threadIdx.x) * 8;
  if (i >= n) return;
  const float4* p = (const float4*)(src + i);
  float4 a = p[0], b = p[1];
  bf16x8 v;
  v[0] = (__bf16)a.x; v[1] = (__bf16)a.y; v[2] = (__bf16)a.z; v[3] = (__bf16)a.w;
  v[4] = (__bf16)b.x; v[5] = (__bf16)b.y; v[6] = (__bf16)b.z; v[7] = (__bf16)b.w;
  *(bf16x8*)(dst + i) = v;
}

// ---------------- transpose fp32[R][C] -> bf16[C][R] ----------------
__global__ __launch_bounds__(256) void transpose_bf16(const float* __restrict__ src,
                                                      __bf16* __restrict__ dst, int R, int C) {
  __shared__ float tile[64 * 65];
  int c0 = blockIdx.x * 64, r0 = blockIdx.y * 64;
  int t = threadIdx.x;
  for (int i = 0; i < 16; ++i) {
    int idx = t + i * 256; int rr = idx >> 6, cc = idx & 63;
    tile[rr * 65 + cc] = src[(size_t)(r0 + rr) * C + (c0 + cc)];
  }
  __syncthreads();
  for (int i = 0; i < 16; ++i) {
    int idx = t + i * 256; int cc = idx >> 6, rr = idx & 63;
    dst[(size_t)(c0 + cc) * R + (r0 + rr)] = (__bf16)tile[rr * 65 + cc];
  }
}

// ---------------- 128x128-tile bf16 MFMA GEMM, A[M][K] @ Bt[N][K]^T ----------------
template<int EPI>
__global__ __launch_bounds__(256) void gemm128(
    const __bf16* __restrict__ A, const __bf16* __restrict__ Bt,
    int M, int N, int K,
    const float* __restrict__ bias0, const float* __restrict__ bias1,
    float* __restrict__ outf,
    __bf16* __restrict__ Qo, __bf16* __restrict__ Ko, __bf16* __restrict__ Vt)
{
  __shared__ __bf16 As[128 * 32];
  __shared__ __bf16 Bs[128 * 32];
  const int m0 = blockIdx.x * 128, n0 = blockIdx.y * 128;
  const int t = threadIdx.x, lane = t & 63, wave = t >> 6;
  const int wr = wave >> 1, wc = wave & 1;
  const int g = lane >> 4, ci = lane & 15;
  f32x4 acc[4][4];
#pragma unroll
  for (int i = 0; i < 4; ++i)
#pragma unroll
    for (int j = 0; j < 4; ++j) acc[i][j] = (f32x4){0.f, 0.f, 0.f, 0.f};

  const char* Ab = (const char*)A;
  const char* Bb = (const char*)Bt;
  for (int k0 = 0; k0 < K; k0 += 32) {
#pragma unroll
    for (int i = 0; i < 2; ++i) {
      int o = wave * 2048 + i * 1024 + lane * 16;
      int row = o >> 6, cb = o & 63;
      gld_lds16(Ab + ((size_t)(m0 + row) * K + k0) * 2 + cb, (char*)As + o);
      gld_lds16(Bb + ((size_t)(n0 + row) * K + k0) * 2 + cb, (char*)Bs + o);
    }
    __syncthreads();
    bf16x8 af[4], bfr[4];
#pragma unroll
    for (int i = 0; i < 4; ++i)
      af[i] = *(const bf16x8*)((const char*)As + (wr * 64 + i * 16 + ci) * 64 + g * 16);
#pragma unroll
    for (int j = 0; j < 4; ++j)
      bfr[j] = *(const bf16x8*)((const char*)Bs + (wc * 64 + j * 16 + ci) * 64 + g * 16);
#pragma unroll
    for (int i = 0; i < 4; ++i)
#pragma unroll
      for (int j = 0; j < 4; ++j)
        acc[i][j] = __builtin_amdgcn_mfma_f32_16x16x32_bf16(af[i], bfr[j], acc[i][j], 0, 0, 0);
    __syncthreads();
  }
#pragma unroll
  for (int j = 0; j < 4; ++j) {
    int c = n0 + wc * 64 + j * 16 + ci;
    float bias;
    if (EPI == 0) bias = (c < 1024) ? bias0[c] : bias1[c - 1024];
    else          bias = bias0[c];
#pragma unroll
    for (int i = 0; i < 4; ++i) {
      int rbase = m0 + wr * 64 + i * 16 + g * 4;
      if (EPI == 1) {
#pragma unroll
        for (int r = 0; r < 4; ++r)
          outf[(size_t)(rbase + r) * 1024 + c] = acc[i][j][r] + bias;
      } else {
        int b = rbase >> 11, n = rbase & 2047;
        if (c < 1024) {
          int h = c >> 6, d = c & 63;
#pragma unroll
          for (int r = 0; r < 4; ++r)
            Qo[(((size_t)(b * 16 + h)) * 2048 + n + r) * 64 + d] =
                (__bf16)((acc[i][j][r] + bias) * QSCALE);
        } else if (c < 2048) {
          int c2 = c - 1024; int h = c2 >> 6, d = c2 & 63;
#pragma unroll
          for (int r = 0; r < 4; ++r)
            Ko[(((size_t)(b * 16 + h)) * 2048 + n + r) * 64 + d] =
                (__bf16)(acc[i][j][r] + bias);
        } else {
          int c2 = c - 2048; int h = c2 >> 6, d = c2 & 63;
          bf16x4 pk;
#pragma unroll
          for (int r = 0; r < 4; ++r) pk[r] = (__bf16)(acc[i][j][r] + bias);
          *(bf16x4*)(Vt + ((size_t)(b * 16 + h) * 64 + d) * 2048 + n) = pk;
        }
      }
    }
  }
}

// ---------------- stats kernel: per (b,h,n) softmax max and 1/sum (exp2 domain) ----
// block = (b, h, n-eighth of 256 rows); 16 waves = 16 n-subtiles of 16 rows.
// K m-tile (128 rows) staged once in LDS, shared by all 16 waves.
__global__ __launch_bounds__(1024) void stats_kernel(
    const __bf16* __restrict__ Q, const __bf16* __restrict__ K,
    float* __restrict__ Smax, float* __restrict__ Sinv)
{
  __shared__ __bf16 Kl[128 * 64];   // [m128][d64], chunk c stored at c^(m&7)
  const int blk = blockIdx.x;
  const int b = blk >> 7, rem = blk & 127;
  const int h = rem >> 3, ns8 = rem & 7;
  const int w = threadIdx.x >> 6, lane = threadIdx.x & 63;
  const int g = lane >> 4, ci = lane & 15;
  const size_t bh = (size_t)(b * 16 + h);
  const __bf16* Qh = Q + bh * 2048 * 64;
  const __bf16* Kh = K + bh * 2048 * 64;
  const int n0 = ns8 * 256 + w * 16;

  bf16x8 qf0 = *(const bf16x8*)(Qh + (size_t)(n0 + ci) * 64 + g * 8);
  bf16x8 qf1 = *(const bf16x8*)(Qh + (size_t)(n0 + ci) * 64 + 32 + g * 8);

  // stage decode (constant per thread)
  const int so = threadIdx.x * 16;
  const int sm = so >> 7;             // m row 0..127
  const int sc = ((so >> 4) & 7) ^ (sm & 7);

  float rm = -3.0e30f, rs = 0.f;
  for (int mt = 0; mt < 2048; mt += 128) {
    gld_lds16(Kh + ((size_t)(mt + sm)) * 64 + sc * 8, (char*)Kl + so);
    __syncthreads();
    f32x4 st[8];
#pragma unroll
    for (int fm = 0; fm < 8; ++fm) {
      int row = fm * 16 + ci;
      bf16x8 ka = *(const bf16x8*)((const char*)Kl + row * 128 + ((g ^ (ci & 7)) * 16));
      bf16x8 kb = *(const bf16x8*)((const char*)Kl + row * 128 + (((4 + g) ^ (ci & 7)) * 16));
      st[fm] = (f32x4){0.f, 0.f, 0.f, 0.f};
      st[fm] = __builtin_amdgcn_mfma_f32_16x16x32_bf16(ka, qf0, st[fm], 0, 0, 0);
      st[fm] = __builtin_amdgcn_mfma_f32_16x16x32_bf16(kb, qf1, st[fm], 0, 0, 0);
    }
    float tm = -3.0e30f;
#pragma unroll
    for (int fm = 0; fm < 8; ++fm)
#pragma unroll
      for (int r = 0; r < 4; ++r) tm = fmaxf(tm, st[fm][r]);
    float nm = fmaxf(rm, tm);
    float ts = 0.f;
#pragma unroll
    for (int fm = 0; fm < 8; ++fm)
#pragma unroll
      for (int r = 0; r < 4; ++r) ts += fexp2(st[fm][r] - nm);
    rs = rs * fexp2(rm - nm) + ts;
    rm = nm;
    __syncthreads();
  }
  // combine the 4 g-groups (lane owns col n=ci; m-space partitioned over g)
#pragma unroll
  for (int off = 16; off <= 32; off <<= 1) {
    float om = __shfl_xor(rm, off, 64);
    float os = __shfl_xor(rs, off, 64);
    float nm = fmaxf(rm, om);
    rs = rs * fexp2(rm - nm) + os * fexp2(om - nm);
    rm = nm;
  }
  if (lane < 16) {
    size_t idx = bh * 2048 + n0 + ci;
    Smax[idx] = rm;
    Sinv[idx] = 1.0f / rs;
  }
}

// ---------------- weights + PV kernel ----------------
// block = (b, n-tile 128, m-chunk 256); 16 waves = 8 n-subtiles x 2 head-halves.
// Each wave processes 8 heads -> K/V LDS tiles shared block-wide; weights are
// h-contiguous in registers -> direct f32x4 stores (no cross-wave transpose).
// O partials atomicAdd'ed into f32 accumulator.
__global__ __launch_bounds__(1024, 4) void attn_w_kernel(
    const __bf16* __restrict__ Q, const __bf16* __restrict__ K, const __bf16* __restrict__ Vt,
    const float* __restrict__ Smax, const float* __restrict__ Sinv,
    float* __restrict__ Wout, float* __restrict__ Oacc)
{
  __shared__ __bf16 Kl[16 * 32 * 64];   // [h][m32][d64] rows 128B, chunk c at c^(m&7)
  __shared__ __bf16 Vl[16 * 64 * 32];   // [h][d64][m32] rows 64B, chunk c at c^(d&1)
  __shared__ __bf16 Pp[16][16][40];     // per-wave P patch: [wave][n16][40] (80B rows)
  const int blk = blockIdx.x;
  const int b = blk >> 7, nt = (blk >> 3) & 15, mc = blk & 7;
  const int n0 = nt * 128, mbase = mc * 256;
  const int wave = threadIdx.x >> 6, lane = threadIdx.x & 63;
  const int ns = wave & 7, hh = wave >> 3;
  const int g = lane >> 4, ci = lane & 15;
  const int nrow = n0 + ns * 16 + ci;
  const __bf16* Qb = Q + (size_t)b * 16 * 2048 * 64;
  const __bf16* Kb = K + (size_t)b * 16 * 2048 * 64;
  const __bf16* Vb = Vt + (size_t)b * 16 * 2048 * 64;

  // stats (lane-local: n = nrow)
  float sm_[8], si_[8];
#pragma unroll
  for (int hi = 0; hi < 8; ++hi) {
    size_t sidx = (size_t)(b * 16 + hh * 8 + hi) * 2048 + nrow;
    sm_[hi] = Smax[sidx];
    si_[hi] = Sinv[sidx];
  }
  // Q B-frags for 8 heads
  bf16x8 qf[8][2];
#pragma unroll
  for (int hi = 0; hi < 8; ++hi) {
    const __bf16* qp = Qb + ((size_t)(hh * 8 + hi) * 2048 + nrow) * 64;
    qf[hi][0] = *(const bf16x8*)(qp + g * 8);
    qf[hi][1] = *(const bf16x8*)(qp + 32 + g * 8);
  }
  f32x4 oacc[8][4];
#pragma unroll
  for (int hi = 0; hi < 8; ++hi)
#pragma unroll
    for (int fd = 0; fd < 4; ++fd) oacc[hi][fd] = (f32x4){0.f, 0.f, 0.f, 0.f};

  // stage decode (constant per thread)
  const int t = threadIdx.x;

  for (int t8 = 0; t8 < 8; ++t8) {
    const int mb = mbase + t8 * 32;
    // stage K tile (64KB, 4 instr/thread)
#pragma unroll
    for (int i = 0; i < 4; ++i) {
      int o = i * 16384 + t * 16;
      int row = o >> 7;                 // h*32+m
      int hq = row >> 5, m = row & 31;
      int c = ((o >> 4) & 7) ^ (m & 7);
      gld_lds16(Kb + ((size_t)hq * 2048 + mb + m) * 64 + c * 8, (char*)Kl + o);
    }
    // stage V tile (64KB)
#pragma unroll
    for (int i = 0; i < 4; ++i) {
      int o = i * 16384 + t * 16;
      int row = o >> 6;                 // h*64+d
      int hq = row >> 6, d = row & 63;
      int c = ((o >> 4) & 3) ^ (d & 1);
      gld_lds16(Vb + ((size_t)hq * 64 + d) * 2048 + mb + c * 8, (char*)Vl + o);
    }
    __syncthreads();

    f32x4 w32[8][2];
#pragma unroll
    for (int hi = 0; hi < 8; ++hi) {
      const int h = hh * 8 + hi;
      f32x4 st[2];
#pragma unroll
      for (int fm = 0; fm < 2; ++fm) {
        int row = h * 32 + fm * 16 + ci;
        bf16x8 ka = *(const bf16x8*)((const char*)Kl + row * 128 + ((g ^ (ci & 7)) * 16));
        bf16x8 kb = *(const bf16x8*)((const char*)Kl + row * 128 + (((4 + g) ^ (ci & 7)) * 16));
        st[fm] = (f32x4){0.f, 0.f, 0.f, 0.f};
        st[fm] = __builtin_amdgcn_mfma_f32_16x16x32_bf16(ka, qf[hi][0], st[fm], 0, 0, 0);
        st[fm] = __builtin_amdgcn_mfma_f32_16x16x32_bf16(kb, qf[hi][1], st[fm], 0, 0, 0);
      }
      // normalized weights (f32 for output) + bf16-packed patch write
#pragma unroll
      for (int fm = 0; fm < 2; ++fm) {
        f32x4 w;
#pragma unroll
        for (int r = 0; r < 4; ++r) w[r] = fexp2(st[fm][r] - sm_[hi]) * si_[hi];
        w32[hi][fm] = w;
        u32* pb = (u32*)((char*)&Pp[wave][ci][0] + (fm * 8 + g * 2) * 4);
        pb[0] = pkbf(w[0], w[1]);
        pb[1] = pkbf(w[2], w[3]);
      }
      // PV A-frag from patch (same-wave LDS, compiler inserts lgkmcnt)
      bf16x8 wf = *(const bf16x8*)((const char*)&Pp[wave][ci][0] + g * 16);
#pragma unroll
      for (int fd = 0; fd < 4; ++fd) {
        int vrow = h * 64 + fd * 16 + ci;
        bf16x8 vf = *(const bf16x8*)((const char*)Vl + vrow * 64 + ((g ^ (ci & 1)) * 16));
        oacc[hi][fd] = __builtin_amdgcn_mfma_f32_16x16x32_bf16(wf, vf, oacc[hi][fd], 0, 0, 0);
      }
    }
    // weights stores: lane covers (n=nrow, m = mb+fm*16+g*4+r, h = hh*8..hh*8+7)
#pragma unroll
    for (int fm = 0; fm < 2; ++fm)
#pragma unroll
      for (int r = 0; r < 4; ++r) {
        int midx = mb + fm * 16 + g * 4 + r;
        float* dst = Wout + ((size_t)(b * 2048 + nrow) * 2048 + midx) * 16 + hh * 8;
        f32x4 v0 = {w32[0][fm][r], w32[1][fm][r], w32[2][fm][r], w32[3][fm][r]};
        f32x4 v1 = {w32[4][fm][r], w32[5][fm][r], w32[6][fm][r], w32[7][fm][r]};
        *(f32x4*)dst = v0;
        *(f32x4*)(dst + 4) = v1;
      }
    __syncthreads();
  }
  // O partial accumulation (PV C-layout: row n = g*4+r, col d = fd*16+ci)
#pragma unroll
  for (int hi = 0; hi < 8; ++hi)
#pragma unroll
    for (int fd = 0; fd < 4; ++fd)
#pragma unroll
      for (int r = 0; r < 4; ++r) {
        int n = n0 + ns * 16 + g * 4 + r;
        atomicAdd(Oacc + ((size_t)(b * 2048 + n)) * 1024 + (hh * 8 + hi) * 64 + fd * 16 + ci,
                  oacc[hi][fd][r]);
      }
}

extern "C" void kernel_launch(void* const* d_in, const int* in_sizes, int n_in,
                              void* d_out, int out_size, void* d_ws, size_t ws_size,
                              hipStream_t stream) {
  const float* queries = (const float*)d_in[0];
  const float* Wq  = (const float*)d_in[1];
  const float* bq  = (const float*)d_in[2];
  const float* Wkv = (const float*)d_in[3];
  const float* bkv = (const float*)d_in[4];
  const float* Wo  = (const float*)d_in[5];
  const float* bo  = (const float*)d_in[6];
  const int Bsz = in_sizes[0] / (2048 * 1024);
  const int M = Bsz * 2048;

  size_t bf16_elems = (size_t)M * 1024 * 5 + (size_t)3072 * 1024 + (size_t)1024 * 1024;
  size_t f32_elems  = (size_t)M * 16 * 2 + (size_t)M * 1024;
  size_t need = bf16_elems * 2 + f32_elems * 4;
  if (ws_size < need) return;

  __bf16* Xbf   = (__bf16*)d_ws;
  __bf16* WcatT = Xbf + (size_t)M * 1024;
  __bf16* WoT   = WcatT + (size_t)3072 * 1024;
  __bf16* Qb    = WoT + (size_t)1024 * 1024;
  __bf16* Kb    = Qb + (size_t)M * 1024;
  __bf16* Vb    = Kb + (size_t)M * 1024;     // Vt [b][h][d][s]
  __bf16* Ob    = Vb + (size_t)M * 1024;
  float*  Smax  = (float*)(Ob + (size_t)M * 1024);
  float*  Sinv  = Smax + (size_t)M * 16;
  float*  Oacc  = Sinv + (size_t)M * 16;

  float* outp = (float*)d_out;
  float* wout = outp + (size_t)M * 1024;

  hipMemsetAsync(Oacc, 0, (size_t)M * 1024 * 4, stream);
  cvt_f32_bf16<<<(M * 1024) / (256 * 8), 256, 0, stream>>>(queries, Xbf, M * 1024);
  transpose_bf16<<<dim3(16, 16), 256, 0, stream>>>(Wq, WcatT, 1024, 1024);
  transpose_bf16<<<dim3(32, 16), 256, 0, stream>>>(Wkv, WcatT + (size_t)1024 * 1024, 1024, 2048);
  transpose_bf16<<<dim3(16, 16), 256, 0, stream>>>(Wo, WoT, 1024, 1024);
  gemm128<0><<<dim3(M / 128, 3072 / 128), 256, 0, stream>>>(
      Xbf, WcatT, M, 3072, 1024, bq, bkv, nullptr, Qb, Kb, Vb);
  stats_kernel<<<Bsz * 128, 1024, 0, stream>>>(Qb, Kb, Smax, Sinv);
  attn_w_kernel<<<Bsz * 128, 1024, 0, stream>>>(Qb, Kb, Vb, Smax, Sinv, wout, Oacc);
  cvt_f32_bf16<<<(M * 1024) / (256 * 8), 256, 0, stream>>>(Oacc, Ob, M * 1024);
  gemm128<1><<<dim3(M / 128, 1024 / 128), 256, 0, stream>>>(
      Ob, WoT, M, 1024, 1024, bo, nullptr, outp, nullptr, nullptr, nullptr);
}

// Round 5
// 527.673 us; speedup vs baseline: 2.1587x; 2.1587x over previous
//
#include <hip/hip_runtime.h>

typedef __bf16 bf16x8 __attribute__((ext_vector_type(8)));
typedef __bf16 bf16x4 __attribute__((ext_vector_type(4)));
typedef float f32x4 __attribute__((ext_vector_type(4)));
typedef unsigned int u32;

// Problem constants: B (runtime), S=2048, D=1024, H=16, hd=64
#define QSCALE 0.18033688011112042f  // hd^-0.5 * log2(e), folded into Q

__device__ __forceinline__ void gld_lds16(const void* gsrc, void* ldst) {
  __builtin_amdgcn_global_load_lds(
      (const __attribute__((address_space(1))) u32*)gsrc,
      (__attribute__((address_space(3))) u32*)ldst, 16, 0, 0);
}

__device__ __forceinline__ float fexp2(float x) {
#if __has_builtin(__builtin_amdgcn_exp2f)
  return __builtin_amdgcn_exp2f(x);
#else
  return exp2f(x);
#endif
}

// ---------------- fp32 -> bf16 elementwise convert ----------------
__global__ __launch_bounds__(256) void cvt_f32_bf16(const float* __restrict__ src,
                                                    __bf16* __restrict__ dst, int n) {
  int i = (blockIdx.x * 256 + threadIdx.x) * 8;
  if (i >= n) return;
  const float4* p = (const float4*)(src + i);
  float4 a = p[0], b = p[1];
  bf16x8 v;
  v[0] = (__bf16)a.x; v[1] = (__bf16)a.y; v[2] = (__bf16)a.z; v[3] = (__bf16)a.w;
  v[4] = (__bf16)b.x; v[5] = (__bf16)b.y; v[6] = (__bf16)b.z; v[7] = (__bf16)b.w;
  *(bf16x8*)(dst + i) = v;
}

// ---------------- transpose fp32[R][C] -> bf16[C][R] ----------------
__global__ __launch_bounds__(256) void transpose_bf16(const float* __restrict__ src,
                                                      __bf16* __restrict__ dst, int R, int C) {
  __shared__ float tile[64 * 65];
  int c0 = blockIdx.x * 64, r0 = blockIdx.y * 64;
  int t = threadIdx.x;
  for (int i = 0; i < 16; ++i) {
    int idx = t + i * 256; int rr = idx >> 6, cc = idx & 63;
    tile[rr * 65 + cc] = src[(size_t)(r0 + rr) * C + (c0 + cc)];
  }
  __syncthreads();
  for (int i = 0; i < 16; ++i) {
    int idx = t + i * 256; int cc = idx >> 6, rr = idx & 63;
    dst[(size_t)(c0 + cc) * R + (r0 + rr)] = (__bf16)tile[rr * 65 + cc];
  }
}

// ---------------- 128x128-tile bf16 MFMA GEMM, A[M][K] @ Bt[N][K]^T ----------------
template<int EPI>
__global__ __launch_bounds__(256) void gemm128(
    const __bf16* __restrict__ A, const __bf16* __restrict__ Bt,
    int M, int N, int K,
    const float* __restrict__ bias0, const float* __restrict__ bias1,
    float* __restrict__ outf,
    __bf16* __restrict__ Qo, __bf16* __restrict__ Ko, __bf16* __restrict__ Vt)
{
  __shared__ __bf16 As[128 * 32];
  __shared__ __bf16 Bs[128 * 32];
  const int m0 = blockIdx.x * 128, n0 = blockIdx.y * 128;
  const int t = threadIdx.x, lane = t & 63, wave = t >> 6;
  const int wr = wave >> 1, wc = wave & 1;
  const int g = lane >> 4, ci = lane & 15;
  f32x4 acc[4][4];
#pragma unroll
  for (int i = 0; i < 4; ++i)
#pragma unroll
    for (int j = 0; j < 4; ++j) acc[i][j] = (f32x4){0.f, 0.f, 0.f, 0.f};

  const char* Ab = (const char*)A;
  const char* Bb = (const char*)Bt;
  for (int k0 = 0; k0 < K; k0 += 32) {
#pragma unroll
    for (int i = 0; i < 2; ++i) {
      int o = wave * 2048 + i * 1024 + lane * 16;
      int row = o >> 6, cb = o & 63;
      gld_lds16(Ab + ((size_t)(m0 + row) * K + k0) * 2 + cb, (char*)As + o);
      gld_lds16(Bb + ((size_t)(n0 + row) * K + k0) * 2 + cb, (char*)Bs + o);
    }
    __syncthreads();
    bf16x8 af[4], bfr[4];
#pragma unroll
    for (int i = 0; i < 4; ++i)
      af[i] = *(const bf16x8*)((const char*)As + (wr * 64 + i * 16 + ci) * 64 + g * 16);
#pragma unroll
    for (int j = 0; j < 4; ++j)
      bfr[j] = *(const bf16x8*)((const char*)Bs + (wc * 64 + j * 16 + ci) * 64 + g * 16);
#pragma unroll
    for (int i = 0; i < 4; ++i)
#pragma unroll
      for (int j = 0; j < 4; ++j)
        acc[i][j] = __builtin_amdgcn_mfma_f32_16x16x32_bf16(af[i], bfr[j], acc[i][j], 0, 0, 0);
    __syncthreads();
  }
#pragma unroll
  for (int j = 0; j < 4; ++j) {
    int c = n0 + wc * 64 + j * 16 + ci;
    float bias;
    if (EPI == 0) bias = (c < 1024) ? bias0[c] : bias1[c - 1024];
    else          bias = bias0[c];
#pragma unroll
    for (int i = 0; i < 4; ++i) {
      int rbase = m0 + wr * 64 + i * 16 + g * 4;
      if (EPI == 1) {
#pragma unroll
        for (int r = 0; r < 4; ++r)
          outf[(size_t)(rbase + r) * 1024 + c] = acc[i][j][r] + bias;
      } else {
        int b = rbase >> 11, n = rbase & 2047;
        if (c < 1024) {
          int h = c >> 6, d = c & 63;
#pragma unroll
          for (int r = 0; r < 4; ++r)
            Qo[(((size_t)(b * 16 + h)) * 2048 + n + r) * 64 + d] =
                (__bf16)((acc[i][j][r] + bias) * QSCALE);
        } else if (c < 2048) {
          int c2 = c - 1024; int h = c2 >> 6, d = c2 & 63;
#pragma unroll
          for (int r = 0; r < 4; ++r)
            Ko[(((size_t)(b * 16 + h)) * 2048 + n + r) * 64 + d] =
                (__bf16)(acc[i][j][r] + bias);
        } else {
          int c2 = c - 2048; int h = c2 >> 6, d = c2 & 63;
          bf16x4 pk;
#pragma unroll
          for (int r = 0; r < 4; ++r) pk[r] = (__bf16)(acc[i][j][r] + bias);
          *(bf16x4*)(Vt + ((size_t)(b * 16 + h) * 64 + d) * 2048 + n) = pk;
        }
      }
    }
  }
}

// ---------------- stats kernel: per (b,h,n) softmax max and 1/sum (exp2 domain) ----
// block = (b, h, n-eighth of 256 rows); 16 waves = 16 n-subtiles of 16 rows.
// K m-tile (128 rows) staged once in LDS, shared by all 16 waves. [validated R3]
__global__ __launch_bounds__(1024) void stats_kernel(
    const __bf16* __restrict__ Q, const __bf16* __restrict__ K,
    float* __restrict__ Smax, float* __restrict__ Sinv)
{
  __shared__ __bf16 Kl[128 * 64];   // [m128][d64], chunk c stored at c^(m&7)
  const int blk = blockIdx.x;
  const int b = blk >> 7, rem = blk & 127;
  const int h = rem >> 3, ns8 = rem & 7;
  const int w = threadIdx.x >> 6, lane = threadIdx.x & 63;
  const int g = lane >> 4, ci = lane & 15;
  const size_t bh = (size_t)(b * 16 + h);
  const __bf16* Qh = Q + bh * 2048 * 64;
  const __bf16* Kh = K + bh * 2048 * 64;
  const int n0 = ns8 * 256 + w * 16;

  bf16x8 qf0 = *(const bf16x8*)(Qh + (size_t)(n0 + ci) * 64 + g * 8);
  bf16x8 qf1 = *(const bf16x8*)(Qh + (size_t)(n0 + ci) * 64 + 32 + g * 8);

  const int so = threadIdx.x * 16;
  const int sm = so >> 7;
  const int sc = ((so >> 4) & 7) ^ (sm & 7);

  float rm = -3.0e30f, rs = 0.f;
  for (int mt = 0; mt < 2048; mt += 128) {
    gld_lds16(Kh + ((size_t)(mt + sm)) * 64 + sc * 8, (char*)Kl + so);
    __syncthreads();
    f32x4 st[8];
#pragma unroll
    for (int fm = 0; fm < 8; ++fm) {
      int row = fm * 16 + ci;
      bf16x8 ka = *(const bf16x8*)((const char*)Kl + row * 128 + ((g ^ (ci & 7)) * 16));
      bf16x8 kb = *(const bf16x8*)((const char*)Kl + row * 128 + (((4 + g) ^ (ci & 7)) * 16));
      st[fm] = (f32x4){0.f, 0.f, 0.f, 0.f};
      st[fm] = __builtin_amdgcn_mfma_f32_16x16x32_bf16(ka, qf0, st[fm], 0, 0, 0);
      st[fm] = __builtin_amdgcn_mfma_f32_16x16x32_bf16(kb, qf1, st[fm], 0, 0, 0);
    }
    float tm = -3.0e30f;
#pragma unroll
    for (int fm = 0; fm < 8; ++fm)
#pragma unroll
      for (int r = 0; r < 4; ++r) tm = fmaxf(tm, st[fm][r]);
    float nm = fmaxf(rm, tm);
    float ts = 0.f;
#pragma unroll
    for (int fm = 0; fm < 8; ++fm)
#pragma unroll
      for (int r = 0; r < 4; ++r) ts += fexp2(st[fm][r] - nm);
    rs = rs * fexp2(rm - nm) + ts;
    rm = nm;
    __syncthreads();
  }
#pragma unroll
  for (int off = 16; off <= 32; off <<= 1) {
    float om = __shfl_xor(rm, off, 64);
    float os = __shfl_xor(rs, off, 64);
    float nm = fmaxf(rm, om);
    rs = rs * fexp2(rm - nm) + os * fexp2(om - nm);
    rm = nm;
  }
  if (lane < 16) {
    size_t idx = bh * 2048 + n0 + ci;
    Smax[idx] = rm;
    Sinv[idx] = 1.0f / rs;
  }
}

// ---------------- weights + PV kernel (v5: R2-validated body, n-tile 32, m-half) ----
// Block = (b, 32 n-rows, m-half 1024); 16 waves = 16 heads; grid = B*128.
// Per m-tile (64 rows): load K/V frags once; then for each 16-row n-subtile run the
// R2-validated sequence: scores -> normalized weights -> W2 (quad-rotated, stride 324)
// -> same-wave PV -> barrier -> cooperative store -> barrier.
// O partials atomicAdd'ed into f32 accumulator (R3-validated chain).
__global__ __launch_bounds__(1024) void attn_w3(
    const __bf16* __restrict__ Q, const __bf16* __restrict__ K, const __bf16* __restrict__ Vt,
    const float* __restrict__ Smax, const float* __restrict__ Sinv,
    float* __restrict__ Wout, float* __restrict__ Oacc)
{
  __shared__ float W2[64 * 324];   // 83 KB [validated R2 layout]
  const int blk = blockIdx.x;
  const int b = blk >> 7, r2 = blk & 127;
  const int mh = r2 >> 6, nt = r2 & 63;
  const int n0 = nt * 32, mstart = mh * 1024;
  const int h = threadIdx.x >> 6;            // wave = head
  const int lane = threadIdx.x & 63;
  const int g = lane >> 4, ci = lane & 15;
  const int h4 = h >> 2, hl = h & 3;
  const size_t bh = (size_t)(b * 16 + h);
  const __bf16* Qh = Q + bh * 2048 * 64;
  const __bf16* Kh = K + bh * 2048 * 64;
  const __bf16* Vh = Vt + bh * 64 * 2048;    // [d][s]

  // softmax stats + Q B-frags for the two 16-row n-subtiles
  float sm_[2], si_[2];
  bf16x8 qf[2][2];
#pragma unroll
  for (int nsub = 0; nsub < 2; ++nsub) {
    size_t idx = bh * 2048 + n0 + nsub * 16 + ci;
    sm_[nsub] = Smax[idx];
    si_[nsub] = Sinv[idx];
    const __bf16* qp = Qh + (size_t)(n0 + nsub * 16 + ci) * 64;
    qf[nsub][0] = *(const bf16x8*)(qp + g * 8);
    qf[nsub][1] = *(const bf16x8*)(qp + 32 + g * 8);
  }
  f32x4 oac[2][4];
#pragma unroll
  for (int nsub = 0; nsub < 2; ++nsub)
#pragma unroll
    for (int fd = 0; fd < 4; ++fd) oac[nsub][fd] = (f32x4){0.f, 0.f, 0.f, 0.f};

  // store-loop identity (constant per thread) [validated R2]
  const int sn = threadIdx.x >> 6, sm = threadIdx.x & 63;
  const int sq = (sm + (sm >> 2)) & 3;
  const float* slds = &W2[sm * 324 + sn * 20];

  for (int mb = mstart; mb < mstart + 1024; mb += 64) {
    // K A-frags (row=m=ci, k=d) — shared by both n-subtiles
    bf16x8 ka[4], kb[4];
#pragma unroll
    for (int fm = 0; fm < 4; ++fm) {
      const __bf16* kp = Kh + (size_t)(mb + fm * 16 + ci) * 64;
      ka[fm] = *(const bf16x8*)(kp + g * 8);
      kb[fm] = *(const bf16x8*)(kp + 32 + g * 8);
    }
    // V B-frags (col=d=fd*16+ci, k=m) — shared by both n-subtiles
    bf16x8 vf[2][4];
#pragma unroll
    for (int kk = 0; kk < 2; ++kk)
#pragma unroll
      for (int fd = 0; fd < 4; ++fd)
        vf[kk][fd] = *(const bf16x8*)(Vh + (size_t)(fd * 16 + ci) * 2048 +
                                      mb + kk * 32 + g * 8);

#pragma unroll
    for (int nsub = 0; nsub < 2; ++nsub) {
      // scores: C-layout col=n=ci, row=m=fm*16+4g+r
      f32x4 st[4];
#pragma unroll
      for (int fm = 0; fm < 4; ++fm) {
        f32x4 s = (f32x4){0.f, 0.f, 0.f, 0.f};
        s = __builtin_amdgcn_mfma_f32_16x16x32_bf16(ka[fm], qf[nsub][0], s, 0, 0, 0);
        s = __builtin_amdgcn_mfma_f32_16x16x32_bf16(kb[fm], qf[nsub][1], s, 0, 0, 0);
        st[fm] = s;
      }
      // normalized weights -> W2 (R2 formula: m*324 + n*20 + p*4 + hl,
      // p = (h4 + m + (m>>2)) & 3)
#pragma unroll
      for (int fm = 0; fm < 4; ++fm)
#pragma unroll
        for (int r = 0; r < 4; ++r) {
          float w = fexp2(st[fm][r] - sm_[nsub]) * si_[nsub];
          int m = fm * 16 + g * 4 + r;
          int p = (h4 + m + (m >> 2)) & 3;
          W2[m * 324 + ci * 20 + p * 4 + hl] = w;
        }
      // PV A-frags from own head column (same-wave LDS) [R2 formula]
#pragma unroll
      for (int kk = 0; kk < 2; ++kk) {
        bf16x8 wf;
#pragma unroll
        for (int j = 0; j < 8; ++j) {
          int m = kk * 32 + g * 8 + j;
          int p = (h4 + m + (m >> 2)) & 3;
          wf[j] = (__bf16)W2[m * 324 + ci * 20 + p * 4 + hl];
        }
#pragma unroll
        for (int fd = 0; fd < 4; ++fd)
          oac[nsub][fd] = __builtin_amdgcn_mfma_f32_16x16x32_bf16(
              wf, vf[kk][fd], oac[nsub][fd], 0, 0, 0);
      }
      __syncthreads();
      // cooperative store: thread -> (n=sn, m=sm), 4x f32x4 [validated R2]
      size_t gbase = (((size_t)(b * 2048 + n0 + nsub * 16 + sn)) * 2048 + mb + sm) * 16;
#pragma unroll
      for (int k4 = 0; k4 < 4; ++k4) {
        int p = (k4 + sq) & 3;
        f32x4 v = *(const f32x4*)(slds + p * 4);
        *(f32x4*)(Wout + gbase + (size_t)k4 * 4) = v;
      }
      __syncthreads();
    }
  }
  // O partial accumulation (PV C-layout: row n = 4g+r, col d = fd*16+ci)
#pragma unroll
  for (int nsub = 0; nsub < 2; ++nsub)
#pragma unroll
    for (int fd = 0; fd < 4; ++fd)
#pragma unroll
      for (int r = 0; r < 4; ++r) {
        int n = n0 + nsub * 16 + g * 4 + r;
        atomicAdd(Oacc + ((size_t)(b * 2048 + n)) * 1024 + h * 64 + fd * 16 + ci,
                  oac[nsub][fd][r]);
      }
}

extern "C" void kernel_launch(void* const* d_in, const int* in_sizes, int n_in,
                              void* d_out, int out_size, void* d_ws, size_t ws_size,
                              hipStream_t stream) {
  const float* queries = (const float*)d_in[0];
  const float* Wq  = (const float*)d_in[1];
  const float* bq  = (const float*)d_in[2];
  const float* Wkv = (const float*)d_in[3];
  const float* bkv = (const float*)d_in[4];
  const float* Wo  = (const float*)d_in[5];
  const float* bo  = (const float*)d_in[6];
  const int Bsz = in_sizes[0] / (2048 * 1024);
  const int M = Bsz * 2048;

  size_t bf16_elems = (size_t)M * 1024 * 5 + (size_t)3072 * 1024 + (size_t)1024 * 1024;
  size_t f32_elems  = (size_t)M * 16 * 2 + (size_t)M * 1024;
  size_t need = bf16_elems * 2 + f32_elems * 4;
  if (ws_size < need) return;

  __bf16* Xbf   = (__bf16*)d_ws;
  __bf16* WcatT = Xbf + (size_t)M * 1024;
  __bf16* WoT   = WcatT + (size_t)3072 * 1024;
  __bf16* Qb    = WoT + (size_t)1024 * 1024;
  __bf16* Kb    = Qb + (size_t)M * 1024;
  __bf16* Vb    = Kb + (size_t)M * 1024;     // Vt [b][h][d][s]
  __bf16* Ob    = Vb + (size_t)M * 1024;
  float*  Smax  = (float*)(Ob + (size_t)M * 1024);
  float*  Sinv  = Smax + (size_t)M * 16;
  float*  Oacc  = Sinv + (size_t)M * 16;

  float* outp = (float*)d_out;
  float* wout = outp + (size_t)M * 1024;

  hipMemsetAsync(Oacc, 0, (size_t)M * 1024 * 4, stream);
  cvt_f32_bf16<<<(M * 1024) / (256 * 8), 256, 0, stream>>>(queries, Xbf, M * 1024);
  transpose_bf16<<<dim3(16, 16), 256, 0, stream>>>(Wq, WcatT, 1024, 1024);
  transpose_bf16<<<dim3(32, 16), 256, 0, stream>>>(Wkv, WcatT + (size_t)1024 * 1024, 1024, 2048);
  transpose_bf16<<<dim3(16, 16), 256, 0, stream>>>(Wo, WoT, 1024, 1024);
  gemm128<0><<<dim3(M / 128, 3072 / 128), 256, 0, stream>>>(
      Xbf, WcatT, M, 3072, 1024, bq, bkv, nullptr, Qb, Kb, Vb);
  stats_kernel<<<Bsz * 128, 1024, 0, stream>>>(Qb, Kb, Smax, Sinv);
  attn_w3<<<Bsz * 128, 1024, 0, stream>>>(Qb, Kb, Vb, Smax, Sinv, wout, Oacc);
  cvt_f32_bf16<<<(M * 1024) / (256 * 8), 256, 0, stream>>>(Oacc, Ob, M * 1024);
  gemm128<1><<<dim3(M / 128, 1024 / 128), 256, 0, stream>>>(
      Ob, WoT, M, 1024, 1024, bo, nullptr, outp, nullptr, nullptr, nullptr);
}

// Round 6
// 457.496 us; speedup vs baseline: 2.4898x; 1.1534x over previous
//
#include <hip/hip_runtime.h>

typedef __bf16 bf16x8 __attribute__((ext_vector_type(8)));
typedef __bf16 bf16x4 __attribute__((ext_vector_type(4)));
typedef float f32x4 __attribute__((ext_vector_type(4)));
typedef unsigned int u32;

// Problem constants: B (runtime), S=2048, D=1024, H=16, hd=64
#define QSCALE 0.18033688011112042f  // hd^-0.5 * log2(e), folded into Q

__device__ __forceinline__ void gld_lds16(const void* gsrc, void* ldst) {
  __builtin_amdgcn_global_load_lds(
      (const __attribute__((address_space(1))) u32*)gsrc,
      (__attribute__((address_space(3))) u32*)ldst, 16, 0, 0);
}

__device__ __forceinline__ float fexp2(float x) {
#if __has_builtin(__builtin_amdgcn_exp2f)
  return __builtin_amdgcn_exp2f(x);
#else
  return exp2f(x);
#endif
}

// ---------------- fp32 -> bf16 elementwise convert ----------------
__global__ __launch_bounds__(256) void cvt_f32_bf16(const float* __restrict__ src,
                                                    __bf16* __restrict__ dst, int n) {
  int i = (blockIdx.x * 256 + threadIdx.x) * 8;
  if (i >= n) return;
  const float4* p = (const float4*)(src + i);
  float4 a = p[0], b = p[1];
  bf16x8 v;
  v[0] = (__bf16)a.x; v[1] = (__bf16)a.y; v[2] = (__bf16)a.z; v[3] = (__bf16)a.w;
  v[4] = (__bf16)b.x; v[5] = (__bf16)b.y; v[6] = (__bf16)b.z; v[7] = (__bf16)b.w;
  *(bf16x8*)(dst + i) = v;
}

// ---------------- transpose fp32[R][C] -> bf16[C][R] ----------------
__global__ __launch_bounds__(256) void transpose_bf16(const float* __restrict__ src,
                                                      __bf16* __restrict__ dst, int R, int C) {
  __shared__ float tile[64 * 65];
  int c0 = blockIdx.x * 64, r0 = blockIdx.y * 64;
  int t = threadIdx.x;
  for (int i = 0; i < 16; ++i) {
    int idx = t + i * 256; int rr = idx >> 6, cc = idx & 63;
    tile[rr * 65 + cc] = src[(size_t)(r0 + rr) * C + (c0 + cc)];
  }
  __syncthreads();
  for (int i = 0; i < 16; ++i) {
    int idx = t + i * 256; int cc = idx >> 6, rr = idx & 63;
    dst[(size_t)(c0 + cc) * R + (r0 + rr)] = (__bf16)tile[rr * 65 + cc];
  }
}

// ---------------- 128x128-tile bf16 MFMA GEMM, A[M][K] @ Bt[N][K]^T ----------------
template<int EPI>
__global__ __launch_bounds__(256) void gemm128(
    const __bf16* __restrict__ A, const __bf16* __restrict__ Bt,
    int M, int N, int K,
    const float* __restrict__ bias0, const float* __restrict__ bias1,
    float* __restrict__ outf,
    __bf16* __restrict__ Qo, __bf16* __restrict__ Ko, __bf16* __restrict__ Vt)
{
  __shared__ __bf16 As[128 * 32];
  __shared__ __bf16 Bs[128 * 32];
  const int m0 = blockIdx.x * 128, n0 = blockIdx.y * 128;
  const int t = threadIdx.x, lane = t & 63, wave = t >> 6;
  const int wr = wave >> 1, wc = wave & 1;
  const int g = lane >> 4, ci = lane & 15;
  f32x4 acc[4][4];
#pragma unroll
  for (int i = 0; i < 4; ++i)
#pragma unroll
    for (int j = 0; j < 4; ++j) acc[i][j] = (f32x4){0.f, 0.f, 0.f, 0.f};

  const char* Ab = (const char*)A;
  const char* Bb = (const char*)Bt;
  for (int k0 = 0; k0 < K; k0 += 32) {
#pragma unroll
    for (int i = 0; i < 2; ++i) {
      int o = wave * 2048 + i * 1024 + lane * 16;
      int row = o >> 6, cb = o & 63;
      gld_lds16(Ab + ((size_t)(m0 + row) * K + k0) * 2 + cb, (char*)As + o);
      gld_lds16(Bb + ((size_t)(n0 + row) * K + k0) * 2 + cb, (char*)Bs + o);
    }
    __syncthreads();
    bf16x8 af[4], bfr[4];
#pragma unroll
    for (int i = 0; i < 4; ++i)
      af[i] = *(const bf16x8*)((const char*)As + (wr * 64 + i * 16 + ci) * 64 + g * 16);
#pragma unroll
    for (int j = 0; j < 4; ++j)
      bfr[j] = *(const bf16x8*)((const char*)Bs + (wc * 64 + j * 16 + ci) * 64 + g * 16);
#pragma unroll
    for (int i = 0; i < 4; ++i)
#pragma unroll
      for (int j = 0; j < 4; ++j)
        acc[i][j] = __builtin_amdgcn_mfma_f32_16x16x32_bf16(af[i], bfr[j], acc[i][j], 0, 0, 0);
    __syncthreads();
  }
#pragma unroll
  for (int j = 0; j < 4; ++j) {
    int c = n0 + wc * 64 + j * 16 + ci;
    float bias;
    if (EPI == 0) bias = (c < 1024) ? bias0[c] : bias1[c - 1024];
    else          bias = bias0[c];
#pragma unroll
    for (int i = 0; i < 4; ++i) {
      int rbase = m0 + wr * 64 + i * 16 + g * 4;
      if (EPI == 1) {
#pragma unroll
        for (int r = 0; r < 4; ++r)
          outf[(size_t)(rbase + r) * 1024 + c] = acc[i][j][r] + bias;
      } else {
        int b = rbase >> 11, n = rbase & 2047;
        if (c < 1024) {
          int h = c >> 6, d = c & 63;
#pragma unroll
          for (int r = 0; r < 4; ++r)
            Qo[(((size_t)(b * 16 + h)) * 2048 + n + r) * 64 + d] =
                (__bf16)((acc[i][j][r] + bias) * QSCALE);
        } else if (c < 2048) {
          int c2 = c - 1024; int h = c2 >> 6, d = c2 & 63;
#pragma unroll
          for (int r = 0; r < 4; ++r)
            Ko[(((size_t)(b * 16 + h)) * 2048 + n + r) * 64 + d] =
                (__bf16)(acc[i][j][r] + bias);
        } else {
          int c2 = c - 2048; int h = c2 >> 6, d = c2 & 63;
          bf16x4 pk;
#pragma unroll
          for (int r = 0; r < 4; ++r) pk[r] = (__bf16)(acc[i][j][r] + bias);
          *(bf16x4*)(Vt + ((size_t)(b * 16 + h) * 64 + d) * 2048 + n) = pk;
        }
      }
    }
  }
}

// ---------------- stats kernel: per (b,h,n) softmax max and 1/sum (exp2 domain) ----
// [validated R3/R5]
__global__ __launch_bounds__(1024) void stats_kernel(
    const __bf16* __restrict__ Q, const __bf16* __restrict__ K,
    float* __restrict__ Smax, float* __restrict__ Sinv)
{
  __shared__ __bf16 Kl[128 * 64];   // [m128][d64], chunk c stored at c^(m&7)
  const int blk = blockIdx.x;
  const int b = blk >> 7, rem = blk & 127;
  const int h = rem >> 3, ns8 = rem & 7;
  const int w = threadIdx.x >> 6, lane = threadIdx.x & 63;
  const int g = lane >> 4, ci = lane & 15;
  const size_t bh = (size_t)(b * 16 + h);
  const __bf16* Qh = Q + bh * 2048 * 64;
  const __bf16* Kh = K + bh * 2048 * 64;
  const int n0 = ns8 * 256 + w * 16;

  bf16x8 qf0 = *(const bf16x8*)(Qh + (size_t)(n0 + ci) * 64 + g * 8);
  bf16x8 qf1 = *(const bf16x8*)(Qh + (size_t)(n0 + ci) * 64 + 32 + g * 8);

  const int so = threadIdx.x * 16;
  const int sm = so >> 7;
  const int sc = ((so >> 4) & 7) ^ (sm & 7);

  float rm = -3.0e30f, rs = 0.f;
  for (int mt = 0; mt < 2048; mt += 128) {
    gld_lds16(Kh + ((size_t)(mt + sm)) * 64 + sc * 8, (char*)Kl + so);
    __syncthreads();
    f32x4 st[8];
#pragma unroll
    for (int fm = 0; fm < 8; ++fm) {
      int row = fm * 16 + ci;
      bf16x8 ka = *(const bf16x8*)((const char*)Kl + row * 128 + ((g ^ (ci & 7)) * 16));
      bf16x8 kb = *(const bf16x8*)((const char*)Kl + row * 128 + (((4 + g) ^ (ci & 7)) * 16));
      st[fm] = (f32x4){0.f, 0.f, 0.f, 0.f};
      st[fm] = __builtin_amdgcn_mfma_f32_16x16x32_bf16(ka, qf0, st[fm], 0, 0, 0);
      st[fm] = __builtin_amdgcn_mfma_f32_16x16x32_bf16(kb, qf1, st[fm], 0, 0, 0);
    }
    float tm = -3.0e30f;
#pragma unroll
    for (int fm = 0; fm < 8; ++fm)
#pragma unroll
      for (int r = 0; r < 4; ++r) tm = fmaxf(tm, st[fm][r]);
    float nm = fmaxf(rm, tm);
    float ts = 0.f;
#pragma unroll
    for (int fm = 0; fm < 8; ++fm)
#pragma unroll
      for (int r = 0; r < 4; ++r) ts += fexp2(st[fm][r] - nm);
    rs = rs * fexp2(rm - nm) + ts;
    rm = nm;
    __syncthreads();
  }
#pragma unroll
  for (int off = 16; off <= 32; off <<= 1) {
    float om = __shfl_xor(rm, off, 64);
    float os = __shfl_xor(rs, off, 64);
    float nm = fmaxf(rm, om);
    rs = rs * fexp2(rm - nm) + os * fexp2(om - nm);
    rm = nm;
  }
  if (lane < 16) {
    size_t idx = bh * 2048 + n0 + ci;
    Smax[idx] = rm;
    Sinv[idx] = 1.0f / rs;
  }
}

// ---------------- weights + PV kernel (v6: 2 blocks/CU, ping-pong W2, 1 barrier) ----
// Block = (b, 16 n-rows, m-half 1024); 16 waves = 16 heads; grid = B*256 -> 2 blocks/CU.
// W2 layout per buffer [m32][n16*17+h] = R1-validated; ping-pong halves barrier count:
//   round r: K/V frags -> scores -> weights into W2[r&1] -> same-wave PV
//            -> ONE barrier -> cooperative coalesced store of W2[r&1].
// Next write of the same buffer is 2 rounds later, strictly after the intervening
// barrier -> race-free with a single barrier per round.
// __launch_bounds__(1024,8) caps VGPR at 64 so two 1024-thread blocks co-reside
// (2x69.6KB LDS = 139KB <= 160KB), overlapping one block's store/drain with the
// other's compute.
__global__ __launch_bounds__(1024, 8) void attn_w5(
    const __bf16* __restrict__ Q, const __bf16* __restrict__ K, const __bf16* __restrict__ Vt,
    const float* __restrict__ Smax, const float* __restrict__ Sinv,
    float* __restrict__ Wout, float* __restrict__ Oacc)
{
  __shared__ float W2[2][32 * 272];   // 2 x 34.8 KB ping-pong
  const int blk = blockIdx.x;
  const int mh = blk & 1;
  const int nt = (blk >> 1) & 127;
  const int b  = blk >> 8;
  const int n0 = nt * 16, mstart = mh * 1024;
  const int h = threadIdx.x >> 6;            // wave = head
  const int lane = threadIdx.x & 63;
  const int g = lane >> 4, ci = lane & 15;
  const size_t bh = (size_t)(b * 16 + h);
  const __bf16* Qh = Q + bh * 2048 * 64;
  const __bf16* Kh = K + bh * 2048 * 64;
  const __bf16* Vh = Vt + bh * 64 * 2048;    // [d][s]

  const float smx = Smax[bh * 2048 + n0 + ci];
  const float sin = Sinv[bh * 2048 + n0 + ci];
  bf16x8 qf0 = *(const bf16x8*)(Qh + (size_t)(n0 + ci) * 64 + g * 8);
  bf16x8 qf1 = *(const bf16x8*)(Qh + (size_t)(n0 + ci) * 64 + 32 + g * 8);

  f32x4 oacc[4];
#pragma unroll
  for (int fd = 0; fd < 4; ++fd) oacc[fd] = (f32x4){0.f, 0.f, 0.f, 0.f};

  for (int rnd = 0; rnd < 32; ++rnd) {
    const int m0 = mstart + rnd * 32;
    float* Wc = &W2[rnd & 1][0];
    // K A-frags (row=m=ci, k=d)
    bf16x8 ka[2], kb[2];
#pragma unroll
    for (int fm = 0; fm < 2; ++fm) {
      const __bf16* kp = Kh + (size_t)(m0 + fm * 16 + ci) * 64;
      ka[fm] = *(const bf16x8*)(kp + g * 8);
      kb[fm] = *(const bf16x8*)(kp + 32 + g * 8);
    }
    // scores: C-layout col=n=ci, row=m=fm*16+4g+r
    f32x4 st[2];
#pragma unroll
    for (int fm = 0; fm < 2; ++fm) {
      f32x4 s = (f32x4){0.f, 0.f, 0.f, 0.f};
      s = __builtin_amdgcn_mfma_f32_16x16x32_bf16(ka[fm], qf0, s, 0, 0, 0);
      s = __builtin_amdgcn_mfma_f32_16x16x32_bf16(kb[fm], qf1, s, 0, 0, 0);
      st[fm] = s;
    }
    // V B-frags (col=d=fd*16+ci, k=m) — vectorized from Vt [d][s]
    bf16x8 vf[4];
#pragma unroll
    for (int fd = 0; fd < 4; ++fd)
      vf[fd] = *(const bf16x8*)(Vh + (size_t)(fd * 16 + ci) * 2048 + m0 + g * 8);
    // normalized weights -> W2[cur] (R1-validated layout m*272 + n*17 + h)
#pragma unroll
    for (int fm = 0; fm < 2; ++fm)
#pragma unroll
      for (int r = 0; r < 4; ++r) {
        float w = fexp2(st[fm][r] - smx) * sin;
        int m = fm * 16 + g * 4 + r;
        Wc[m * 272 + ci * 17 + h] = w;
      }
    // PV A-frag from own head column (same-wave LDS, no barrier needed)
    bf16x8 wf;
#pragma unroll
    for (int j = 0; j < 8; ++j)
      wf[j] = (__bf16)Wc[(g * 8 + j) * 272 + ci * 17 + h];
#pragma unroll
    for (int fd = 0; fd < 4; ++fd)
      oacc[fd] = __builtin_amdgcn_mfma_f32_16x16x32_bf16(wf, vf[fd], oacc[fd], 0, 0, 0);

    __syncthreads();
    // cooperative coalesced store: [n][m][h] contiguous runs (R1-validated)
    size_t wbase = (((size_t)(b * 2048 + n0)) * 2048 + m0) * 16;
#pragma unroll
    for (int it = 0; it < 8; ++it) {
      int idx = threadIdx.x + it * 1024;
      int n = idx >> 9, m = (idx >> 4) & 31, hh = idx & 15;
      Wout[wbase + ((size_t)n * 2048 + m) * 16 + hh] = Wc[m * 272 + n * 17 + hh];
    }
  }
  // O partial accumulation (PV C-layout: row n = 4g+r, col d = fd*16+ci)
#pragma unroll
  for (int fd = 0; fd < 4; ++fd)
#pragma unroll
    for (int r = 0; r < 4; ++r) {
      int n = n0 + g * 4 + r;
      atomicAdd(Oacc + ((size_t)(b * 2048 + n)) * 1024 + h * 64 + fd * 16 + ci,
                oacc[fd][r]);
    }
}

extern "C" void kernel_launch(void* const* d_in, const int* in_sizes, int n_in,
                              void* d_out, int out_size, void* d_ws, size_t ws_size,
                              hipStream_t stream) {
  const float* queries = (const float*)d_in[0];
  const float* Wq  = (const float*)d_in[1];
  const float* bq  = (const float*)d_in[2];
  const float* Wkv = (const float*)d_in[3];
  const float* bkv = (const float*)d_in[4];
  const float* Wo  = (const float*)d_in[5];
  const float* bo  = (const float*)d_in[6];
  const int Bsz = in_sizes[0] / (2048 * 1024);
  const int M = Bsz * 2048;

  size_t bf16_elems = (size_t)M * 1024 * 5 + (size_t)3072 * 1024 + (size_t)1024 * 1024;
  size_t f32_elems  = (size_t)M * 16 * 2 + (size_t)M * 1024;
  size_t need = bf16_elems * 2 + f32_elems * 4;
  if (ws_size < need) return;

  __bf16* Xbf   = (__bf16*)d_ws;
  __bf16* WcatT = Xbf + (size_t)M * 1024;
  __bf16* WoT   = WcatT + (size_t)3072 * 1024;
  __bf16* Qb    = WoT + (size_t)1024 * 1024;
  __bf16* Kb    = Qb + (size_t)M * 1024;
  __bf16* Vb    = Kb + (size_t)M * 1024;     // Vt [b][h][d][s]
  __bf16* Ob    = Vb + (size_t)M * 1024;
  float*  Smax  = (float*)(Ob + (size_t)M * 1024);
  float*  Sinv  = Smax + (size_t)M * 16;
  float*  Oacc  = Sinv + (size_t)M * 16;

  float* outp = (float*)d_out;
  float* wout = outp + (size_t)M * 1024;

  hipMemsetAsync(Oacc, 0, (size_t)M * 1024 * 4, stream);
  cvt_f32_bf16<<<(M * 1024) / (256 * 8), 256, 0, stream>>>(queries, Xbf, M * 1024);
  transpose_bf16<<<dim3(16, 16), 256, 0, stream>>>(Wq, WcatT, 1024, 1024);
  transpose_bf16<<<dim3(32, 16), 256, 0, stream>>>(Wkv, WcatT + (size_t)1024 * 1024, 1024, 2048);
  transpose_bf16<<<dim3(16, 16), 256, 0, stream>>>(Wo, WoT, 1024, 1024);
  gemm128<0><<<dim3(M / 128, 3072 / 128), 256, 0, stream>>>(
      Xbf, WcatT, M, 3072, 1024, bq, bkv, nullptr, Qb, Kb, Vb);
  stats_kernel<<<Bsz * 128, 1024, 0, stream>>>(Qb, Kb, Smax, Sinv);
  attn_w5<<<Bsz * 256, 1024, 0, stream>>>(Qb, Kb, Vb, Smax, Sinv, wout, Oacc);
  cvt_f32_bf16<<<(M * 1024) / (256 * 8), 256, 0, stream>>>(Oacc, Ob, M * 1024);
  gemm128<1><<<dim3(M / 128, 1024 / 128), 256, 0, stream>>>(
      Ob, WoT, M, 1024, 1024, bo, nullptr, outp, nullptr, nullptr, nullptr);
}

// Round 8
// 350.626 us; speedup vs baseline: 3.2487x; 1.3048x over previous
//
#include <hip/hip_runtime.h>

typedef __bf16 bf16x8 __attribute__((ext_vector_type(8)));
typedef __bf16 bf16x4 __attribute__((ext_vector_type(4)));
typedef __bf16 bf16x2 __attribute__((ext_vector_type(2)));
typedef float f32x4 __attribute__((ext_vector_type(4)));
typedef unsigned int u32;

// Problem constants: B (runtime), S=2048, D=1024, H=16, hd=64
#define QSCALE 0.18033688011112042f  // hd^-0.5 * log2(e), folded into Q

__device__ __forceinline__ void gld_lds16(const void* gsrc, void* ldst) {
  __builtin_amdgcn_global_load_lds(
      (const __attribute__((address_space(1))) u32*)gsrc,
      (__attribute__((address_space(3))) u32*)ldst, 16, 0, 0);
}

__device__ __forceinline__ float fexp2(float x) {
#if __has_builtin(__builtin_amdgcn_exp2f)
  return __builtin_amdgcn_exp2f(x);
#else
  return exp2f(x);
#endif
}

__device__ __forceinline__ u32 pkbf(float a, float b) {
  bf16x2 t; t[0] = (__bf16)a; t[1] = (__bf16)b;
  return __builtin_bit_cast(u32, t);
}

// ---------------- fp32 -> bf16 elementwise convert ----------------
__global__ __launch_bounds__(256) void cvt_f32_bf16(const float* __restrict__ src,
                                                    __bf16* __restrict__ dst, int n) {
  int i = (blockIdx.x * 256 + threadIdx.x) * 8;
  if (i >= n) return;
  const float4* p = (const float4*)(src + i);
  float4 a = p[0], b = p[1];
  bf16x8 v;
  v[0] = (__bf16)a.x; v[1] = (__bf16)a.y; v[2] = (__bf16)a.z; v[3] = (__bf16)a.w;
  v[4] = (__bf16)b.x; v[5] = (__bf16)b.y; v[6] = (__bf16)b.z; v[7] = (__bf16)b.w;
  *(bf16x8*)(dst + i) = v;
}

// ---------------- transpose fp32[R][C] -> bf16[C][R] ----------------
__global__ __launch_bounds__(256) void transpose_bf16(const float* __restrict__ src,
                                                      __bf16* __restrict__ dst, int R, int C) {
  __shared__ float tile[64 * 65];
  int c0 = blockIdx.x * 64, r0 = blockIdx.y * 64;
  int t = threadIdx.x;
  for (int i = 0; i < 16; ++i) {
    int idx = t + i * 256; int rr = idx >> 6, cc = idx & 63;
    tile[rr * 65 + cc] = src[(size_t)(r0 + rr) * C + (c0 + cc)];
  }
  __syncthreads();
  for (int i = 0; i < 16; ++i) {
    int idx = t + i * 256; int cc = idx >> 6, rr = idx & 63;
    dst[(size_t)(c0 + cc) * R + (r0 + rr)] = (__bf16)tile[rr * 65 + cc];
  }
}

// ---------------- 128x128-tile bf16 MFMA GEMM, A[M][K] @ Bt[N][K]^T ----------------
template<int EPI>
__global__ __launch_bounds__(256) void gemm128(
    const __bf16* __restrict__ A, const __bf16* __restrict__ Bt,
    int M, int N, int K,
    const float* __restrict__ bias0, const float* __restrict__ bias1,
    float* __restrict__ outf,
    __bf16* __restrict__ Qo, __bf16* __restrict__ Ko, __bf16* __restrict__ Vt)
{
  __shared__ __bf16 As[128 * 32];
  __shared__ __bf16 Bs[128 * 32];
  const int m0 = blockIdx.x * 128, n0 = blockIdx.y * 128;
  const int t = threadIdx.x, lane = t & 63, wave = t >> 6;
  const int wr = wave >> 1, wc = wave & 1;
  const int g = lane >> 4, ci = lane & 15;
  f32x4 acc[4][4];
#pragma unroll
  for (int i = 0; i < 4; ++i)
#pragma unroll
    for (int j = 0; j < 4; ++j) acc[i][j] = (f32x4){0.f, 0.f, 0.f, 0.f};

  const char* Ab = (const char*)A;
  const char* Bb = (const char*)Bt;
  for (int k0 = 0; k0 < K; k0 += 32) {
#pragma unroll
    for (int i = 0; i < 2; ++i) {
      int o = wave * 2048 + i * 1024 + lane * 16;
      int row = o >> 6, cb = o & 63;
      gld_lds16(Ab + ((size_t)(m0 + row) * K + k0) * 2 + cb, (char*)As + o);
      gld_lds16(Bb + ((size_t)(n0 + row) * K + k0) * 2 + cb, (char*)Bs + o);
    }
    __syncthreads();
    bf16x8 af[4], bfr[4];
#pragma unroll
    for (int i = 0; i < 4; ++i)
      af[i] = *(const bf16x8*)((const char*)As + (wr * 64 + i * 16 + ci) * 64 + g * 16);
#pragma unroll
    for (int j = 0; j < 4; ++j)
      bfr[j] = *(const bf16x8*)((const char*)Bs + (wc * 64 + j * 16 + ci) * 64 + g * 16);
#pragma unroll
    for (int i = 0; i < 4; ++i)
#pragma unroll
      for (int j = 0; j < 4; ++j)
        acc[i][j] = __builtin_amdgcn_mfma_f32_16x16x32_bf16(af[i], bfr[j], acc[i][j], 0, 0, 0);
    __syncthreads();
  }
#pragma unroll
  for (int j = 0; j < 4; ++j) {
    int c = n0 + wc * 64 + j * 16 + ci;
    float bias;
    if (EPI == 0) bias = (c < 1024) ? bias0[c] : bias1[c - 1024];
    else          bias = bias0[c];
#pragma unroll
    for (int i = 0; i < 4; ++i) {
      int rbase = m0 + wr * 64 + i * 16 + g * 4;
      if (EPI == 1) {
#pragma unroll
        for (int r = 0; r < 4; ++r)
          outf[(size_t)(rbase + r) * 1024 + c] = acc[i][j][r] + bias;
      } else {
        int b = rbase >> 11, n = rbase & 2047;
        if (c < 1024) {
          int h = c >> 6, d = c & 63;
#pragma unroll
          for (int r = 0; r < 4; ++r)
            Qo[(((size_t)(b * 16 + h)) * 2048 + n + r) * 64 + d] =
                (__bf16)((acc[i][j][r] + bias) * QSCALE);
        } else if (c < 2048) {
          int c2 = c - 1024; int h = c2 >> 6, d = c2 & 63;
#pragma unroll
          for (int r = 0; r < 4; ++r)
            Ko[(((size_t)(b * 16 + h)) * 2048 + n + r) * 64 + d] =
                (__bf16)(acc[i][j][r] + bias);
        } else {
          int c2 = c - 2048; int h = c2 >> 6, d = c2 & 63;
          bf16x4 pk;
#pragma unroll
          for (int r = 0; r < 4; ++r) pk[r] = (__bf16)(acc[i][j][r] + bias);
          *(bf16x4*)(Vt + ((size_t)(b * 16 + h) * 64 + d) * 2048 + n) = pk;
        }
      }
    }
  }
}

// ---------------- statspv: softmax stats + flash PV (O single-writer) ----------------
// block = (b, h, n-eighth of 256 rows); 16 waves = 16 n-subtiles of 16 rows.
// K m-tile (128 rows) staged once in LDS, shared by all 16 waves [validated R3/R5].
// KEY FIX vs R7: stats live at row n=ci (QK^T C-col) but oacc rows are n=g*4+r
// (PV C-row). The rescale and final 1/sum must be shuffled from lane g*4+r.
__global__ __launch_bounds__(1024) void statspv_kernel(
    const __bf16* __restrict__ Q, const __bf16* __restrict__ K, const __bf16* __restrict__ Vt,
    float* __restrict__ Smax, float* __restrict__ Sinv, __bf16* __restrict__ Ob)
{
  __shared__ __bf16 Kl[128 * 64];   // [m128][d64], chunk c stored at c^(m&7)
  __shared__ __bf16 Pp[16][16][40]; // per-wave P patch: [wave][n16][40] (80B rows)
  const int blk = blockIdx.x;
  const int b = blk >> 7, rem = blk & 127;
  const int h = rem >> 3, ns8 = rem & 7;
  const int w = threadIdx.x >> 6, lane = threadIdx.x & 63;
  const int g = lane >> 4, ci = lane & 15;
  const size_t bh = (size_t)(b * 16 + h);
  const __bf16* Qh = Q + bh * 2048 * 64;
  const __bf16* Kh = K + bh * 2048 * 64;
  const __bf16* Vh = Vt + bh * 64 * 2048;   // [d][s]
  const int n0 = ns8 * 256 + w * 16;

  bf16x8 qf0 = *(const bf16x8*)(Qh + (size_t)(n0 + ci) * 64 + g * 8);
  bf16x8 qf1 = *(const bf16x8*)(Qh + (size_t)(n0 + ci) * 64 + 32 + g * 8);

  const int so = threadIdx.x * 16;
  const int sm = so >> 7;
  const int sc = ((so >> 4) & 7) ^ (sm & 7);

  float rm = -3.0e30f, rs = 0.f;
  f32x4 oacc[4];
#pragma unroll
  for (int fd = 0; fd < 4; ++fd) oacc[fd] = (f32x4){0.f, 0.f, 0.f, 0.f};

  for (int mt = 0; mt < 2048; mt += 128) {
    gld_lds16(Kh + ((size_t)(mt + sm)) * 64 + sc * 8, (char*)Kl + so);
    __syncthreads();
    f32x4 st[8];
#pragma unroll
    for (int fm = 0; fm < 8; ++fm) {
      int row = fm * 16 + ci;
      bf16x8 ka = *(const bf16x8*)((const char*)Kl + row * 128 + ((g ^ (ci & 7)) * 16));
      bf16x8 kb = *(const bf16x8*)((const char*)Kl + row * 128 + (((4 + g) ^ (ci & 7)) * 16));
      st[fm] = (f32x4){0.f, 0.f, 0.f, 0.f};
      st[fm] = __builtin_amdgcn_mfma_f32_16x16x32_bf16(ka, qf0, st[fm], 0, 0, 0);
      st[fm] = __builtin_amdgcn_mfma_f32_16x16x32_bf16(kb, qf1, st[fm], 0, 0, 0);
    }
    // per-round row max for col n=ci (cross-g combine so all 4 g-lanes agree)
    float tm = -3.0e30f;
#pragma unroll
    for (int fm = 0; fm < 8; ++fm)
#pragma unroll
      for (int r = 0; r < 4; ++r) tm = fmaxf(tm, st[fm][r]);
    tm = fmaxf(tm, __shfl_xor(tm, 16, 64));
    tm = fmaxf(tm, __shfl_xor(tm, 32, 64));
    float nm = fmaxf(rm, tm);
    float scale = fexp2(rm - nm);       // scale for row n = ci
    rs *= scale;
    // FIX: oacc rows are n = g*4+r -> fetch those rows' scales from lanes g*4+r
    f32x4 rsc;
#pragma unroll
    for (int r = 0; r < 4; ++r) rsc[r] = __shfl(scale, g * 4 + r, 64);
#pragma unroll
    for (int fd = 0; fd < 4; ++fd)
#pragma unroll
      for (int r = 0; r < 4; ++r) oacc[fd][r] *= rsc[r];
    rm = nm;
    // PV + sum, one 32-m slice at a time (P bf16 patch, R2/R3-validated layout)
    float ts = 0.f;
#pragma unroll
    for (int kk2 = 0; kk2 < 4; ++kk2) {
#pragma unroll
      for (int fm2 = 0; fm2 < 2; ++fm2) {
        f32x4 s = st[kk2 * 2 + fm2];
        f32x4 wv;
#pragma unroll
        for (int r = 0; r < 4; ++r) { wv[r] = fexp2(s[r] - nm); ts += wv[r]; }
        u32* pb = (u32*)((char*)&Pp[w][ci][0] + (fm2 * 8 + g * 2) * 4);
        pb[0] = pkbf(wv[0], wv[1]);
        pb[1] = pkbf(wv[2], wv[3]);
      }
      bf16x8 pa = *(const bf16x8*)((const char*)&Pp[w][ci][0] + g * 16);
#pragma unroll
      for (int fd = 0; fd < 4; ++fd) {
        bf16x8 vf = *(const bf16x8*)(Vh + (size_t)(fd * 16 + ci) * 2048 +
                                     mt + kk2 * 32 + g * 8);
        oacc[fd] = __builtin_amdgcn_mfma_f32_16x16x32_bf16(pa, vf, oacc[fd], 0, 0, 0);
      }
    }
    rs += ts;
    __syncthreads();
  }
  // combine per-lane partial sums across the 4 g-groups (rm already common)
#pragma unroll
  for (int off = 16; off <= 32; off <<= 1) {
    float om = __shfl_xor(rm, off, 64);
    float os = __shfl_xor(rs, off, 64);
    float nm = fmaxf(rm, om);
    rs = rs * fexp2(rm - nm) + os * fexp2(om - nm);
    rm = nm;
  }
  const float inv = 1.0f / rs;          // for row n = ci
  if (lane < 16) {
    size_t idx = bh * 2048 + n0 + ci;
    Smax[idx] = rm;
    Sinv[idx] = inv;
  }
  // FIX: O write rows are n = g*4+r -> fetch those rows' inv from lanes g*4+r
  f32x4 rinv;
#pragma unroll
  for (int r = 0; r < 4; ++r) rinv[r] = __shfl(inv, g * 4 + r, 64);
#pragma unroll
  for (int fd = 0; fd < 4; ++fd)
#pragma unroll
    for (int r = 0; r < 4; ++r) {
      int n = n0 + g * 4 + r;
      Ob[((size_t)(b * 2048 + n)) * 1024 + h * 64 + fd * 16 + ci] =
          (__bf16)(oacc[fd][r] * rinv[r]);
    }
}

// ---------------- weights-only kernel (v7) ----------------
// Block = (b, n-tile 32, m-quarter 512); 16 waves = 16 heads; grid = B*256.
// No V, no PV, no O -> 2 blocks/CU (LDS 2x34.8KB x 2 blocks = 139KB).
// Per round (32 m): load K frags once (shared by both 16-row n-subtiles);
//   compute nsub0 -> W2[0]; bar; {store W2[0] || compute nsub1 -> W2[1]}; bar;
//   {store W2[1] || next round}. Buffer reuse always >= 1 barrier away.
__global__ __launch_bounds__(1024, 8) void attn_w7(
    const __bf16* __restrict__ Q, const __bf16* __restrict__ K,
    const float* __restrict__ Smax, const float* __restrict__ Sinv,
    float* __restrict__ Wout)
{
  __shared__ float W2[2][32 * 272];   // 2 x 34.8 KB (nsub ping-pong)
  // bijective XCD swizzle: each XCD gets a contiguous 64-block chunk = one (b, mq)
  const int nwg = gridDim.x, cpx = nwg >> 3;
  const int o = blockIdx.x;
  const int blk = (o & 7) * cpx + (o >> 3);
  const int b = blk >> 8, r = blk & 255;
  const int mq = r >> 6, nt = r & 63;
  const int n0 = nt * 32, mstart = mq * 512;
  const int h = threadIdx.x >> 6;            // wave = head
  const int lane = threadIdx.x & 63;
  const int g = lane >> 4, ci = lane & 15;
  const size_t bh = (size_t)(b * 16 + h);
  const __bf16* Qh = Q + bh * 2048 * 64;
  const __bf16* Kh = K + bh * 2048 * 64;

  float sm_[2], si_[2];
  bf16x8 qf[2][2];
#pragma unroll
  for (int nsub = 0; nsub < 2; ++nsub) {
    size_t idx = bh * 2048 + n0 + nsub * 16 + ci;
    sm_[nsub] = Smax[idx];
    si_[nsub] = Sinv[idx];
    const __bf16* qp = Qh + (size_t)(n0 + nsub * 16 + ci) * 64;
    qf[nsub][0] = *(const bf16x8*)(qp + g * 8);
    qf[nsub][1] = *(const bf16x8*)(qp + 32 + g * 8);
  }

  for (int rnd = 0; rnd < 16; ++rnd) {
    const int m0 = mstart + rnd * 32;
    // K A-frags (row=m=ci, k=d), shared by both n-subtiles
    bf16x8 ka[2], kb[2];
#pragma unroll
    for (int fm = 0; fm < 2; ++fm) {
      const __bf16* kp = Kh + (size_t)(m0 + fm * 16 + ci) * 64;
      ka[fm] = *(const bf16x8*)(kp + g * 8);
      kb[fm] = *(const bf16x8*)(kp + 32 + g * 8);
    }
    // ---- nsub 0: scores -> weights -> W2[0] ----
#pragma unroll
    for (int fm = 0; fm < 2; ++fm) {
      f32x4 s = (f32x4){0.f, 0.f, 0.f, 0.f};
      s = __builtin_amdgcn_mfma_f32_16x16x32_bf16(ka[fm], qf[0][0], s, 0, 0, 0);
      s = __builtin_amdgcn_mfma_f32_16x16x32_bf16(kb[fm], qf[0][1], s, 0, 0, 0);
#pragma unroll
      for (int r = 0; r < 4; ++r) {
        float wv = fexp2(s[r] - sm_[0]) * si_[0];
        int m = fm * 16 + g * 4 + r;
        W2[0][m * 272 + ci * 17 + h] = wv;
      }
    }
    __syncthreads();
    // ---- store W2[0] (rows n0..n0+15) overlapped with nsub 1 compute ----
    {
      size_t wbase = (((size_t)(b * 2048 + n0)) * 2048 + m0) * 16;
#pragma unroll
      for (int it = 0; it < 8; ++it) {
        int idx = threadIdx.x + it * 1024;
        int n = idx >> 9, m = (idx >> 4) & 31, hh = idx & 15;
        Wout[wbase + ((size_t)n * 2048 + m) * 16 + hh] = W2[0][m * 272 + n * 17 + hh];
      }
    }
#pragma unroll
    for (int fm = 0; fm < 2; ++fm) {
      f32x4 s = (f32x4){0.f, 0.f, 0.f, 0.f};
      s = __builtin_amdgcn_mfma_f32_16x16x32_bf16(ka[fm], qf[1][0], s, 0, 0, 0);
      s = __builtin_amdgcn_mfma_f32_16x16x32_bf16(kb[fm], qf[1][1], s, 0, 0, 0);
#pragma unroll
      for (int r = 0; r < 4; ++r) {
        float wv = fexp2(s[r] - sm_[1]) * si_[1];
        int m = fm * 16 + g * 4 + r;
        W2[1][m * 272 + ci * 17 + h] = wv;
      }
    }
    __syncthreads();
    // ---- store W2[1] (rows n0+16..n0+31) overlapped with next round ----
    {
      size_t wbase = (((size_t)(b * 2048 + n0 + 16)) * 2048 + m0) * 16;
#pragma unroll
      for (int it = 0; it < 8; ++it) {
        int idx = threadIdx.x + it * 1024;
        int n = idx >> 9, m = (idx >> 4) & 31, hh = idx & 15;
        Wout[wbase + ((size_t)n * 2048 + m) * 16 + hh] = W2[1][m * 272 + n * 17 + hh];
      }
    }
  }
}

extern "C" void kernel_launch(void* const* d_in, const int* in_sizes, int n_in,
                              void* d_out, int out_size, void* d_ws, size_t ws_size,
                              hipStream_t stream) {
  const float* queries = (const float*)d_in[0];
  const float* Wq  = (const float*)d_in[1];
  const float* bq  = (const float*)d_in[2];
  const float* Wkv = (const float*)d_in[3];
  const float* bkv = (const float*)d_in[4];
  const float* Wo  = (const float*)d_in[5];
  const float* bo  = (const float*)d_in[6];
  const int Bsz = in_sizes[0] / (2048 * 1024);
  const int M = Bsz * 2048;

  size_t bf16_elems = (size_t)M * 1024 * 5 + (size_t)3072 * 1024 + (size_t)1024 * 1024;
  size_t f32_elems  = (size_t)M * 16 * 2;
  size_t need = bf16_elems * 2 + f32_elems * 4;
  if (ws_size < need) return;

  __bf16* Xbf   = (__bf16*)d_ws;
  __bf16* WcatT = Xbf + (size_t)M * 1024;
  __bf16* WoT   = WcatT + (size_t)3072 * 1024;
  __bf16* Qb    = WoT + (size_t)1024 * 1024;
  __bf16* Kb    = Qb + (size_t)M * 1024;
  __bf16* Vb    = Kb + (size_t)M * 1024;     // Vt [b][h][d][s]
  __bf16* Ob    = Vb + (size_t)M * 1024;
  float*  Smax  = (float*)(Ob + (size_t)M * 1024);
  float*  Sinv  = Smax + (size_t)M * 16;

  float* outp = (float*)d_out;
  float* wout = outp + (size_t)M * 1024;

  cvt_f32_bf16<<<(M * 1024) / (256 * 8), 256, 0, stream>>>(queries, Xbf, M * 1024);
  transpose_bf16<<<dim3(16, 16), 256, 0, stream>>>(Wq, WcatT, 1024, 1024);
  transpose_bf16<<<dim3(32, 16), 256, 0, stream>>>(Wkv, WcatT + (size_t)1024 * 1024, 1024, 2048);
  transpose_bf16<<<dim3(16, 16), 256, 0, stream>>>(Wo, WoT, 1024, 1024);
  gemm128<0><<<dim3(M / 128, 3072 / 128), 256, 0, stream>>>(
      Xbf, WcatT, M, 3072, 1024, bq, bkv, nullptr, Qb, Kb, Vb);
  statspv_kernel<<<Bsz * 128, 1024, 0, stream>>>(Qb, Kb, Vb, Smax, Sinv, Ob);
  attn_w7<<<Bsz * 256, 1024, 0, stream>>>(Qb, Kb, Smax, Sinv, wout);
  gemm128<1><<<dim3(M / 128, 1024 / 128), 256, 0, stream>>>(
      Ob, WoT, M, 1024, 1024, bo, nullptr, outp, nullptr, nullptr, nullptr);
}

// Round 9
// 330.237 us; speedup vs baseline: 3.4493x; 1.0617x over previous
//
#include <hip/hip_runtime.h>

typedef __bf16 bf16x8 __attribute__((ext_vector_type(8)));
typedef __bf16 bf16x4 __attribute__((ext_vector_type(4)));
typedef __bf16 bf16x2 __attribute__((ext_vector_type(2)));
typedef float f32x4 __attribute__((ext_vector_type(4)));
typedef unsigned int u32;

// Problem constants: B (runtime), S=2048, D=1024, H=16, hd=64
#define QSCALE 0.18033688011112042f  // hd^-0.5 * log2(e), folded into Q

__device__ __forceinline__ void gld_lds16(const void* gsrc, void* ldst) {
  __builtin_amdgcn_global_load_lds(
      (const __attribute__((address_space(1))) u32*)gsrc,
      (__attribute__((address_space(3))) u32*)ldst, 16, 0, 0);
}

__device__ __forceinline__ float fexp2(float x) {
#if __has_builtin(__builtin_amdgcn_exp2f)
  return __builtin_amdgcn_exp2f(x);
#else
  return exp2f(x);
#endif
}

__device__ __forceinline__ u32 pkbf(float a, float b) {
  bf16x2 t; t[0] = (__bf16)a; t[1] = (__bf16)b;
  return __builtin_bit_cast(u32, t);
}

// ---------------- fp32 -> bf16 elementwise convert ----------------
__global__ __launch_bounds__(256) void cvt_f32_bf16(const float* __restrict__ src,
                                                    __bf16* __restrict__ dst, int n) {
  int i = (blockIdx.x * 256 + threadIdx.x) * 8;
  if (i >= n) return;
  const float4* p = (const float4*)(src + i);
  float4 a = p[0], b = p[1];
  bf16x8 v;
  v[0] = (__bf16)a.x; v[1] = (__bf16)a.y; v[2] = (__bf16)a.z; v[3] = (__bf16)a.w;
  v[4] = (__bf16)b.x; v[5] = (__bf16)b.y; v[6] = (__bf16)b.z; v[7] = (__bf16)b.w;
  *(bf16x8*)(dst + i) = v;
}

// ---------------- transpose fp32[R][C] -> bf16[C][R] ----------------
__global__ __launch_bounds__(256) void transpose_bf16(const float* __restrict__ src,
                                                      __bf16* __restrict__ dst, int R, int C) {
  __shared__ float tile[64 * 65];
  int c0 = blockIdx.x * 64, r0 = blockIdx.y * 64;
  int t = threadIdx.x;
  for (int i = 0; i < 16; ++i) {
    int idx = t + i * 256; int rr = idx >> 6, cc = idx & 63;
    tile[rr * 65 + cc] = src[(size_t)(r0 + rr) * C + (c0 + cc)];
  }
  __syncthreads();
  for (int i = 0; i < 16; ++i) {
    int idx = t + i * 256; int cc = idx >> 6, rr = idx & 63;
    dst[(size_t)(c0 + cc) * R + (r0 + rr)] = (__bf16)tile[rr * 65 + cc];
  }
}

// ---------------- 128x128-tile bf16 MFMA GEMM, A[M][K] @ Bt[N][K]^T ----------------
template<int EPI>
__global__ __launch_bounds__(256) void gemm128(
    const __bf16* __restrict__ A, const __bf16* __restrict__ Bt,
    int M, int N, int K,
    const float* __restrict__ bias0, const float* __restrict__ bias1,
    float* __restrict__ outf,
    __bf16* __restrict__ Qo, __bf16* __restrict__ Ko, __bf16* __restrict__ Vt)
{
  __shared__ __bf16 As[128 * 32];
  __shared__ __bf16 Bs[128 * 32];
  const int m0 = blockIdx.x * 128, n0 = blockIdx.y * 128;
  const int t = threadIdx.x, lane = t & 63, wave = t >> 6;
  const int wr = wave >> 1, wc = wave & 1;
  const int g = lane >> 4, ci = lane & 15;
  f32x4 acc[4][4];
#pragma unroll
  for (int i = 0; i < 4; ++i)
#pragma unroll
    for (int j = 0; j < 4; ++j) acc[i][j] = (f32x4){0.f, 0.f, 0.f, 0.f};

  const char* Ab = (const char*)A;
  const char* Bb = (const char*)Bt;
  for (int k0 = 0; k0 < K; k0 += 32) {
#pragma unroll
    for (int i = 0; i < 2; ++i) {
      int o = wave * 2048 + i * 1024 + lane * 16;
      int row = o >> 6, cb = o & 63;
      gld_lds16(Ab + ((size_t)(m0 + row) * K + k0) * 2 + cb, (char*)As + o);
      gld_lds16(Bb + ((size_t)(n0 + row) * K + k0) * 2 + cb, (char*)Bs + o);
    }
    __syncthreads();
    bf16x8 af[4], bfr[4];
#pragma unroll
    for (int i = 0; i < 4; ++i)
      af[i] = *(const bf16x8*)((const char*)As + (wr * 64 + i * 16 + ci) * 64 + g * 16);
#pragma unroll
    for (int j = 0; j < 4; ++j)
      bfr[j] = *(const bf16x8*)((const char*)Bs + (wc * 64 + j * 16 + ci) * 64 + g * 16);
#pragma unroll
    for (int i = 0; i < 4; ++i)
#pragma unroll
      for (int j = 0; j < 4; ++j)
        acc[i][j] = __builtin_amdgcn_mfma_f32_16x16x32_bf16(af[i], bfr[j], acc[i][j], 0, 0, 0);
    __syncthreads();
  }
#pragma unroll
  for (int j = 0; j < 4; ++j) {
    int c = n0 + wc * 64 + j * 16 + ci;
    float bias;
    if (EPI == 0) bias = (c < 1024) ? bias0[c] : bias1[c - 1024];
    else          bias = bias0[c];
#pragma unroll
    for (int i = 0; i < 4; ++i) {
      int rbase = m0 + wr * 64 + i * 16 + g * 4;
      if (EPI == 1) {
#pragma unroll
        for (int r = 0; r < 4; ++r)
          outf[(size_t)(rbase + r) * 1024 + c] = acc[i][j][r] + bias;
      } else {
        int b = rbase >> 11, n = rbase & 2047;
        if (c < 1024) {
          int h = c >> 6, d = c & 63;
#pragma unroll
          for (int r = 0; r < 4; ++r)
            Qo[(((size_t)(b * 16 + h)) * 2048 + n + r) * 64 + d] =
                (__bf16)((acc[i][j][r] + bias) * QSCALE);
        } else if (c < 2048) {
          int c2 = c - 1024; int h = c2 >> 6, d = c2 & 63;
#pragma unroll
          for (int r = 0; r < 4; ++r)
            Ko[(((size_t)(b * 16 + h)) * 2048 + n + r) * 64 + d] =
                (__bf16)(acc[i][j][r] + bias);
        } else {
          int c2 = c - 2048; int h = c2 >> 6, d = c2 & 63;
          bf16x4 pk;
#pragma unroll
          for (int r = 0; r < 4; ++r) pk[r] = (__bf16)(acc[i][j][r] + bias);
          *(bf16x4*)(Vt + ((size_t)(b * 16 + h) * 64 + d) * 2048 + n) = pk;
        }
      }
    }
  }
}

// ---------------- statspv: softmax stats + flash PV (O single-writer) ----------------
// block = (b, h, n-eighth of 256 rows); 16 waves = 16 n-subtiles of 16 rows.
// v9: K double-buffered — stage tile t+1 BEFORE computing tile t, ONE barrier/round.
// Race safety: all LDS reads of buf c drain at the round barrier (lgkmcnt(0));
// the overwrite of c is issued after that barrier. Stage vmcnt drains at the same
// barrier, hidden under the 128-row compute.
// Stats row mapping [validated R8]: stats at row n=ci; oacc rows n=g*4+r -> shuffle.
__global__ __launch_bounds__(1024) void statspv_kernel(
    const __bf16* __restrict__ Q, const __bf16* __restrict__ K, const __bf16* __restrict__ Vt,
    float* __restrict__ Smax, float* __restrict__ Sinv, __bf16* __restrict__ Ob)
{
  __shared__ __bf16 Kl[2][128 * 64]; // [m128][d64], chunk c stored at c^(m&7); dbuf
  __shared__ __bf16 Pp[16][16][40];  // per-wave P patch: [wave][n16][40] (80B rows)
  const int blk = blockIdx.x;
  const int b = blk >> 7, rem = blk & 127;
  const int h = rem >> 3, ns8 = rem & 7;
  const int w = threadIdx.x >> 6, lane = threadIdx.x & 63;
  const int g = lane >> 4, ci = lane & 15;
  const size_t bh = (size_t)(b * 16 + h);
  const __bf16* Qh = Q + bh * 2048 * 64;
  const __bf16* Kh = K + bh * 2048 * 64;
  const __bf16* Vh = Vt + bh * 64 * 2048;   // [d][s]
  const int n0 = ns8 * 256 + w * 16;

  bf16x8 qf0 = *(const bf16x8*)(Qh + (size_t)(n0 + ci) * 64 + g * 8);
  bf16x8 qf1 = *(const bf16x8*)(Qh + (size_t)(n0 + ci) * 64 + 32 + g * 8);

  const int so = threadIdx.x * 16;
  const int sm = so >> 7;
  const int sc = ((so >> 4) & 7) ^ (sm & 7);

  float rm = -3.0e30f, rs = 0.f;
  f32x4 oacc[4];
#pragma unroll
  for (int fd = 0; fd < 4; ++fd) oacc[fd] = (f32x4){0.f, 0.f, 0.f, 0.f};

  // prologue: stage tile 0
  gld_lds16(Kh + ((size_t)sm) * 64 + sc * 8, (char*)Kl[0] + so);
  __syncthreads();
  int cur = 0;

  for (int mt = 0; mt < 2048; mt += 128) {
    // issue next tile's stage FIRST (hides under this tile's compute)
    if (mt + 128 < 2048)
      gld_lds16(Kh + ((size_t)(mt + 128 + sm)) * 64 + sc * 8, (char*)Kl[cur ^ 1] + so);
    const char* Kc = (const char*)Kl[cur];
    f32x4 st[8];
#pragma unroll
    for (int fm = 0; fm < 8; ++fm) {
      int row = fm * 16 + ci;
      bf16x8 ka = *(const bf16x8*)(Kc + row * 128 + ((g ^ (ci & 7)) * 16));
      bf16x8 kb = *(const bf16x8*)(Kc + row * 128 + (((4 + g) ^ (ci & 7)) * 16));
      st[fm] = (f32x4){0.f, 0.f, 0.f, 0.f};
      st[fm] = __builtin_amdgcn_mfma_f32_16x16x32_bf16(ka, qf0, st[fm], 0, 0, 0);
      st[fm] = __builtin_amdgcn_mfma_f32_16x16x32_bf16(kb, qf1, st[fm], 0, 0, 0);
    }
    // per-round row max for col n=ci (cross-g combine so all 4 g-lanes agree)
    float tm = -3.0e30f;
#pragma unroll
    for (int fm = 0; fm < 8; ++fm)
#pragma unroll
      for (int r = 0; r < 4; ++r) tm = fmaxf(tm, st[fm][r]);
    tm = fmaxf(tm, __shfl_xor(tm, 16, 64));
    tm = fmaxf(tm, __shfl_xor(tm, 32, 64));
    float nm = fmaxf(rm, tm);
    float scale = fexp2(rm - nm);       // scale for row n = ci
    rs *= scale;
    // oacc rows are n = g*4+r -> fetch those rows' scales from lanes g*4+r
    f32x4 rsc;
#pragma unroll
    for (int r = 0; r < 4; ++r) rsc[r] = __shfl(scale, g * 4 + r, 64);
#pragma unroll
    for (int fd = 0; fd < 4; ++fd)
#pragma unroll
      for (int r = 0; r < 4; ++r) oacc[fd][r] *= rsc[r];
    rm = nm;
    // PV + sum, one 32-m slice at a time (P bf16 patch, validated layout)
    float ts = 0.f;
#pragma unroll
    for (int kk2 = 0; kk2 < 4; ++kk2) {
#pragma unroll
      for (int fm2 = 0; fm2 < 2; ++fm2) {
        f32x4 s = st[kk2 * 2 + fm2];
        f32x4 wv;
#pragma unroll
        for (int r = 0; r < 4; ++r) { wv[r] = fexp2(s[r] - nm); ts += wv[r]; }
        u32* pb = (u32*)((char*)&Pp[w][ci][0] + (fm2 * 8 + g * 2) * 4);
        pb[0] = pkbf(wv[0], wv[1]);
        pb[1] = pkbf(wv[2], wv[3]);
      }
      bf16x8 pa = *(const bf16x8*)((const char*)&Pp[w][ci][0] + g * 16);
#pragma unroll
      for (int fd = 0; fd < 4; ++fd) {
        bf16x8 vf = *(const bf16x8*)(Vh + (size_t)(fd * 16 + ci) * 2048 +
                                     mt + kk2 * 32 + g * 8);
        oacc[fd] = __builtin_amdgcn_mfma_f32_16x16x32_bf16(pa, vf, oacc[fd], 0, 0, 0);
      }
    }
    rs += ts;
    __syncthreads();
    cur ^= 1;
  }
  // combine per-lane partial sums across the 4 g-groups (rm already common)
#pragma unroll
  for (int off = 16; off <= 32; off <<= 1) {
    float om = __shfl_xor(rm, off, 64);
    float os = __shfl_xor(rs, off, 64);
    float nm = fmaxf(rm, om);
    rs = rs * fexp2(rm - nm) + os * fexp2(om - nm);
    rm = nm;
  }
  const float inv = 1.0f / rs;          // for row n = ci
  if (lane < 16) {
    size_t idx = bh * 2048 + n0 + ci;
    Smax[idx] = rm;
    Sinv[idx] = inv;
  }
  // O write rows are n = g*4+r -> fetch those rows' inv from lanes g*4+r
  f32x4 rinv;
#pragma unroll
  for (int r = 0; r < 4; ++r) rinv[r] = __shfl(inv, g * 4 + r, 64);
#pragma unroll
  for (int fd = 0; fd < 4; ++fd)
#pragma unroll
    for (int r = 0; r < 4; ++r) {
      int n = n0 + g * 4 + r;
      Ob[((size_t)(b * 2048 + n)) * 1024 + h * 64 + fd * 16 + ci] =
          (__bf16)(oacc[fd][r] * rinv[r]);
    }
}

// ---------------- weights-only kernel (v9) ----------------
// Block = (b, n-tile 32, m-quarter 512); 16 waves = 16 heads; grid = B*256.
// 2 blocks/CU (LDS 2x34.8KB x 2 blocks = 139KB).
// v9 change: store loop gathers an h-quad from LDS (4x ds_read_b32, layout
// unchanged) and issues ONE nontemporal global_store_dwordx4 — VMEM store
// instructions 8 -> 2 per thread per phase; same bytes, element-for-element
// identical mapping to the validated scalar loop. nt keeps K/Q L2-resident.
__global__ __launch_bounds__(1024, 8) void attn_w7(
    const __bf16* __restrict__ Q, const __bf16* __restrict__ K,
    const float* __restrict__ Smax, const float* __restrict__ Sinv,
    float* __restrict__ Wout)
{
  __shared__ float W2[2][32 * 272];   // 2 x 34.8 KB (nsub ping-pong)
  // bijective XCD swizzle: each XCD gets a contiguous 64-block chunk = one (b, mq)
  const int nwg = gridDim.x, cpx = nwg >> 3;
  const int o = blockIdx.x;
  const int blk = (o & 7) * cpx + (o >> 3);
  const int b = blk >> 8, r = blk & 255;
  const int mq = r >> 6, nt = r & 63;
  const int n0 = nt * 32, mstart = mq * 512;
  const int h = threadIdx.x >> 6;            // wave = head
  const int lane = threadIdx.x & 63;
  const int g = lane >> 4, ci = lane & 15;
  const size_t bh = (size_t)(b * 16 + h);
  const __bf16* Qh = Q + bh * 2048 * 64;
  const __bf16* Kh = K + bh * 2048 * 64;

  float sm_[2], si_[2];
  bf16x8 qf[2][2];
#pragma unroll
  for (int nsub = 0; nsub < 2; ++nsub) {
    size_t idx = bh * 2048 + n0 + nsub * 16 + ci;
    sm_[nsub] = Smax[idx];
    si_[nsub] = Sinv[idx];
    const __bf16* qp = Qh + (size_t)(n0 + nsub * 16 + ci) * 64;
    qf[nsub][0] = *(const bf16x8*)(qp + g * 8);
    qf[nsub][1] = *(const bf16x8*)(qp + 32 + g * 8);
  }

  for (int rnd = 0; rnd < 16; ++rnd) {
    const int m0 = mstart + rnd * 32;
    // K A-frags (row=m=ci, k=d), shared by both n-subtiles
    bf16x8 ka[2], kb[2];
#pragma unroll
    for (int fm = 0; fm < 2; ++fm) {
      const __bf16* kp = Kh + (size_t)(m0 + fm * 16 + ci) * 64;
      ka[fm] = *(const bf16x8*)(kp + g * 8);
      kb[fm] = *(const bf16x8*)(kp + 32 + g * 8);
    }
    // ---- nsub 0: scores -> weights -> W2[0] ----
#pragma unroll
    for (int fm = 0; fm < 2; ++fm) {
      f32x4 s = (f32x4){0.f, 0.f, 0.f, 0.f};
      s = __builtin_amdgcn_mfma_f32_16x16x32_bf16(ka[fm], qf[0][0], s, 0, 0, 0);
      s = __builtin_amdgcn_mfma_f32_16x16x32_bf16(kb[fm], qf[0][1], s, 0, 0, 0);
#pragma unroll
      for (int r = 0; r < 4; ++r) {
        float wv = fexp2(s[r] - sm_[0]) * si_[0];
        int m = fm * 16 + g * 4 + r;
        W2[0][m * 272 + ci * 17 + h] = wv;
      }
    }
    __syncthreads();
    // ---- store W2[0] (rows n0..n0+15) overlapped with nsub 1 compute ----
    {
      size_t wbase = (((size_t)(b * 2048 + n0)) * 2048 + m0) * 16;
#pragma unroll
      for (int it = 0; it < 2; ++it) {
        int slot = threadIdx.x + it * 1024;       // slot = n*128 + m*4 + hq
        int n = slot >> 7, m = (slot >> 2) & 31, hq = slot & 3;
        const float* src = &W2[0][m * 272 + n * 17 + hq * 4];
        f32x4 v = {src[0], src[1], src[2], src[3]};
        __builtin_nontemporal_store(
            v, (f32x4*)(Wout + wbase + ((size_t)n * 2048 + m) * 16 + hq * 4));
      }
    }
#pragma unroll
    for (int fm = 0; fm < 2; ++fm) {
      f32x4 s = (f32x4){0.f, 0.f, 0.f, 0.f};
      s = __builtin_amdgcn_mfma_f32_16x16x32_bf16(ka[fm], qf[1][0], s, 0, 0, 0);
      s = __builtin_amdgcn_mfma_f32_16x16x32_bf16(kb[fm], qf[1][1], s, 0, 0, 0);
#pragma unroll
      for (int r = 0; r < 4; ++r) {
        float wv = fexp2(s[r] - sm_[1]) * si_[1];
        int m = fm * 16 + g * 4 + r;
        W2[1][m * 272 + ci * 17 + h] = wv;
      }
    }
    __syncthreads();
    // ---- store W2[1] (rows n0+16..n0+31) overlapped with next round ----
    {
      size_t wbase = (((size_t)(b * 2048 + n0 + 16)) * 2048 + m0) * 16;
#pragma unroll
      for (int it = 0; it < 2; ++it) {
        int slot = threadIdx.x + it * 1024;
        int n = slot >> 7, m = (slot >> 2) & 31, hq = slot & 3;
        const float* src = &W2[1][m * 272 + n * 17 + hq * 4];
        f32x4 v = {src[0], src[1], src[2], src[3]};
        __builtin_nontemporal_store(
            v, (f32x4*)(Wout + wbase + ((size_t)n * 2048 + m) * 16 + hq * 4));
      }
    }
  }
}

extern "C" void kernel_launch(void* const* d_in, const int* in_sizes, int n_in,
                              void* d_out, int out_size, void* d_ws, size_t ws_size,
                              hipStream_t stream) {
  const float* queries = (const float*)d_in[0];
  const float* Wq  = (const float*)d_in[1];
  const float* bq  = (const float*)d_in[2];
  const float* Wkv = (const float*)d_in[3];
  const float* bkv = (const float*)d_in[4];
  const float* Wo  = (const float*)d_in[5];
  const float* bo  = (const float*)d_in[6];
  const int Bsz = in_sizes[0] / (2048 * 1024);
  const int M = Bsz * 2048;

  size_t bf16_elems = (size_t)M * 1024 * 5 + (size_t)3072 * 1024 + (size_t)1024 * 1024;
  size_t f32_elems  = (size_t)M * 16 * 2;
  size_t need = bf16_elems * 2 + f32_elems * 4;
  if (ws_size < need) return;

  __bf16* Xbf   = (__bf16*)d_ws;
  __bf16* WcatT = Xbf + (size_t)M * 1024;
  __bf16* WoT   = WcatT + (size_t)3072 * 1024;
  __bf16* Qb    = WoT + (size_t)1024 * 1024;
  __bf16* Kb    = Qb + (size_t)M * 1024;
  __bf16* Vb    = Kb + (size_t)M * 1024;     // Vt [b][h][d][s]
  __bf16* Ob    = Vb + (size_t)M * 1024;
  float*  Smax  = (float*)(Ob + (size_t)M * 1024);
  float*  Sinv  = Smax + (size_t)M * 16;

  float* outp = (float*)d_out;
  float* wout = outp + (size_t)M * 1024;

  cvt_f32_bf16<<<(M * 1024) / (256 * 8), 256, 0, stream>>>(queries, Xbf, M * 1024);
  transpose_bf16<<<dim3(16, 16), 256, 0, stream>>>(Wq, WcatT, 1024, 1024);
  transpose_bf16<<<dim3(32, 16), 256, 0, stream>>>(Wkv, WcatT + (size_t)1024 * 1024, 1024, 2048);
  transpose_bf16<<<dim3(16, 16), 256, 0, stream>>>(Wo, WoT, 1024, 1024);
  gemm128<0><<<dim3(M / 128, 3072 / 128), 256, 0, stream>>>(
      Xbf, WcatT, M, 3072, 1024, bq, bkv, nullptr, Qb, Kb, Vb);
  statspv_kernel<<<Bsz * 128, 1024, 0, stream>>>(Qb, Kb, Vb, Smax, Sinv, Ob);
  attn_w7<<<Bsz * 256, 1024, 0, stream>>>(Qb, Kb, Smax, Sinv, wout);
  gemm128<1><<<dim3(M / 128, 1024 / 128), 256, 0, stream>>>(
      Ob, WoT, M, 1024, 1024, bo, nullptr, outp, nullptr, nullptr, nullptr);
}